// Round 2
// baseline (317.404 us; speedup 1.0000x reference)
//
#include <hip/hip_runtime.h>

typedef unsigned short u16;
typedef unsigned int u32;
typedef __attribute__((ext_vector_type(8))) short short8;
typedef __attribute__((ext_vector_type(4))) short s16x4;
typedef __attribute__((ext_vector_type(4))) float f32x4;

__device__ __forceinline__ float b2f(u16 u) {
    union { u32 i; float f; } v; v.i = ((u32)u) << 16; return v.f;
}
__device__ __forceinline__ u16 f2b(float f) {
    union { u32 i; float f; } v; v.f = f;
    u32 u = v.i;
    return (u16)((u + 0x7FFFu + ((u >> 16) & 1u)) >> 16);
}
__device__ __forceinline__ f32x4 zero4() {
    f32x4 v; v[0] = 0.f; v[1] = 0.f; v[2] = 0.f; v[3] = 0.f; return v;
}
// packed f32x2 -> bf16x2 (RNE); low 16 bits = first arg (m240 recipe)
__device__ __forceinline__ u32 cvtpk(float lo, float hi) {
    u32 d;
    asm("v_cvt_pk_bf16_f32 %0, %1, %2" : "=v"(d) : "v"(lo), "v"(hi));
    return d;
}

// ---------------------------------------------------------------------------
// fp32 -> bf16 convert (one-time staging; 33 MB total ~ 10us at HBM rate).
// ---------------------------------------------------------------------------
__global__ void convert_kernel(const float* __restrict__ src, u16* __restrict__ dst,
                               int n8) {
    const int stride = gridDim.x * blockDim.x;
    for (int i = blockIdx.x * blockDim.x + threadIdx.x; i < n8; i += stride) {
        const float* s = src + (size_t)i * 8;
        float4 a = ((const float4*)s)[0];
        float4 b = ((const float4*)s)[1];
        short8 o;
        o[0] = (short)f2b(a.x); o[1] = (short)f2b(a.y);
        o[2] = (short)f2b(a.z); o[3] = (short)f2b(a.w);
        o[4] = (short)f2b(b.x); o[5] = (short)f2b(b.y);
        o[6] = (short)f2b(b.z); o[7] = (short)f2b(b.w);
        ((short8*)dst)[i] = o;
    }
}

// ---------------------------------------------------------------------------
// Tiled bf16 MFMA GEMM: C = A[M,K] x B[K,N] + bias[N]; A,B bf16; bias fp32.
// 128x128 tile, BK=32, 4 waves x 4x4 frags of 16x16x32.
// MODE 0: scatter bf16 into Q/K/V [b,h,s,d]. MODE 1: fp32 store to Of [M,N].
// R13: bijective XCD swizzle (T1): nwg = 1152 / 384, both % 8 == 0; each XCD
// gets consecutive tiles -> operand panels L2-resident. Tiles are computed
// identically under any block->tile mapping, so this cannot affect values.
// ---------------------------------------------------------------------------
template <int MODE>
__global__ __launch_bounds__(256, 2) void gemm_bias_kernel(
    const u16* __restrict__ A, const u16* __restrict__ B,
    const float* __restrict__ bias,
    u16* __restrict__ O0, u16* __restrict__ O1, u16* __restrict__ O2,
    float* __restrict__ Of,
    int M, int N, int K)
{
    __shared__ u16 As[128][40];   // [m][k]
    __shared__ u16 Bs[128][36];   // [n][k] transposed

    const int tid = threadIdx.x;
    const int nwgx = gridDim.x;
    const int nwg = nwgx * gridDim.y;
    int lin = blockIdx.y * nwgx + blockIdx.x;
    lin = (lin & 7) * (nwg >> 3) + (lin >> 3);   // bijective: nwg % 8 == 0
    const int m0 = (lin / nwgx) * 128, n0 = (lin % nwgx) * 128;
    const int lane = tid & 63, w = tid >> 6;
    const int quad = lane >> 4, c = lane & 15;
    const int wm = (w & 1) * 64, wn = (w >> 1) * 64;

    f32x4 acc[4][4];
#pragma unroll
    for (int i = 0; i < 4; i++)
#pragma unroll
        for (int j = 0; j < 4; j++) acc[i][j] = zero4();

    const int arow = tid >> 2, acol = (tid & 3) * 8;  // A: 128 rows x 32 k
    const int kp = tid >> 4;                          // B: k-pair 0..15
    const int bnc = (tid & 15) * 8;                   // B: n-group

    for (int k0 = 0; k0 < K; k0 += 32) {
        short8 a0 = *(const short8*)(A + (size_t)(m0 + arow) * K + k0 + acol);
        short8 a1 = *(const short8*)(A + (size_t)(m0 + arow + 64) * K + k0 + acol);
        short8 bl0 = *(const short8*)(B + (size_t)(k0 + 2 * kp) * N + n0 + bnc);
        short8 bl1 = *(const short8*)(B + (size_t)(k0 + 2 * kp + 1) * N + n0 + bnc);

        __syncthreads();  // previous iteration's frag reads done
        *(short8*)&As[arow][acol] = a0;
        *(short8*)&As[arow + 64][acol] = a1;
#pragma unroll
        for (int j = 0; j < 8; j++) {
            u32 pk = (u32)(u16)bl0[j] | ((u32)(u16)bl1[j] << 16);
            *(u32*)&Bs[bnc + j][2 * kp] = pk;
        }
        __syncthreads();

        short8 af[4], bfr[4];
#pragma unroll
        for (int mi = 0; mi < 4; mi++)
            af[mi] = *(const short8*)&As[wm + mi * 16 + c][quad * 8];
#pragma unroll
        for (int ni = 0; ni < 4; ni++) {
            union { short8 v8; s16x4 v4[2]; } u;
            u.v4[0] = *(const s16x4*)&Bs[wn + ni * 16 + c][quad * 8];
            u.v4[1] = *(const s16x4*)&Bs[wn + ni * 16 + c][quad * 8 + 4];
            bfr[ni] = u.v8;
        }
#pragma unroll
        for (int mi = 0; mi < 4; mi++)
#pragma unroll
            for (int ni = 0; ni < 4; ni++)
                acc[mi][ni] = __builtin_amdgcn_mfma_f32_16x16x32_bf16(
                    af[mi], bfr[ni], acc[mi][ni], 0, 0, 0);
    }

#pragma unroll
    for (int ni = 0; ni < 4; ni++) {
        const int gc = n0 + wn + ni * 16 + c;
        const float bv = bias[gc];
        if (MODE == 0) {
            const int which = gc / 768;
            const int e = gc - which * 768;
            const int hh = e >> 6, d = e & 63;
            u16* op = (which == 0) ? O0 : (which == 1 ? O1 : O2);
#pragma unroll
            for (int mi = 0; mi < 4; mi++)
#pragma unroll
                for (int r = 0; r < 4; r++) {
                    const int gr = m0 + wm + mi * 16 + quad * 4 + r;
                    const int bb = gr >> 11, s = gr & 2047;
                    op[(((size_t)bb * 12 + hh) * 2048 + s) * 64 + d] =
                        f2b(acc[mi][ni][r] + bv);
                }
        } else {
#pragma unroll
            for (int mi = 0; mi < 4; mi++)
#pragma unroll
                for (int r = 0; r < 4; r++) {
                    const int gr = m0 + wm + mi * 16 + quad * 4 + r;
                    Of[(size_t)gr * N + gc] = acc[mi][ni][r] + bv;
                }
        }
    }
}

// ---------------------------------------------------------------------------
// Flash attention, KB=64, NO-MAX softmax. R13: R11-proven layouts + targeted
// fixes only (R12's tr-read layout rewrite failed verification; reverted):
//   - P-write repack: shfl_xor(.,1) pairs k-adjacent columns across even/odd
//     lanes; v_cvt_pk_bf16_f32 packs; 8 conflict-free u32 stores replace 16
//     4-way-conflicted u16 stores + 16 f2b (counter theory: P-write was the
//     dominant term of the 2.05e7 SQ_LDS_BANK_CONFLICT).
//   - mask as additive bias: bf16(-29952) staged once for whole sequence;
//     p = __expf(fma(s, 0.125, bias)) underflows to exact 0 when masked.
//   - T14: next K/V tile loads issued right after this tile's LDS writes;
//     raw s_barrier + lgkmcnt(0)-only sync keeps them in flight (m214 +17%).
//   - T5: setprio(1) around MFMA clusters (attn-positive, m191).
// grid (48, 32): head fastest -> XCD-pinned K/V (3 MB / L2).
// ---------------------------------------------------------------------------
__global__ __launch_bounds__(256) void attn_kernel(
    const u16* __restrict__ Q, const u16* __restrict__ Kv,
    const u16* __restrict__ Vv, const int* __restrict__ attmask,
    u16* __restrict__ Y)
{
    const int S = 2048, D = 64, NH = 12;
    __shared__ u16 Ks[64][72];        // [pos][d]
    __shared__ u16 Vs[64][68];        // [d][pos]
    __shared__ u16 Ps[4][16][72];     // per-wave P: [qrow][pos]
    __shared__ u16 msb[2048];         // bf16 additive bias: 0 or -29952

    const int tid = threadIdx.x;
    const int w = tid >> 6, lane = tid & 63;
    const int quad = lane >> 4, c = lane & 15;
    const int bh = blockIdx.x;        // 0..47
    const int qt = blockIdx.y;        // 0..31
    const int b = bh / NH, h = bh - b * NH;

    const u16* Qh = Q + (size_t)bh * S * D;
    const u16* Kh = Kv + (size_t)bh * S * D;
    const u16* Vh = Vv + (size_t)bh * S * D;
    const int q0 = qt * 64 + w * 16;

    short8 aq0 = *(const short8*)&Qh[(size_t)(q0 + c) * D + quad * 8];
    short8 aq1 = *(const short8*)&Qh[(size_t)(q0 + c) * D + 32 + quad * 8];

    // whole-sequence mask bias, staged once (bf16(-30000) = 0xC6EA = -29952;
    // exp underflows to exactly 0, matching R11's cndmask-to-zero semantics)
    for (int i = tid; i < S; i += 256)
        msb[i] = (attmask[b * S + i] == 0) ? (u16)0xC6EA : (u16)0;

    f32x4 o_acc[4];
#pragma unroll
    for (int i = 0; i < 4; i++) o_acc[i] = zero4();
    float l_r[4] = {0.f, 0.f, 0.f, 0.f};

    const int kpos = tid >> 2, kd = (tid & 3) * 8;
    const int p2 = tid >> 3, vd = (tid & 7) * 8;

    // T14 prologue: issue tile-0 loads
    short8 k0r = *(const short8*)&Kh[(size_t)kpos * D + kd];
    short8 k1r = *(const short8*)&Kh[(size_t)kpos * D + kd + 32];
    short8 v0r = *(const short8*)&Vh[(size_t)(2 * p2) * D + vd];
    short8 v1r = *(const short8*)&Vh[(size_t)(2 * p2 + 1) * D + vd];

    for (int kt = 0; kt < S / 64; kt++) {
        // ---- staging (raw barriers: vmcnt NOT drained -> prefetch in flight)
        asm volatile("" ::: "memory");
        __builtin_amdgcn_s_barrier();     // prev tile's LDS reads all retired
        asm volatile("" ::: "memory");
        *(short8*)&Ks[kpos][kd] = k0r;    // compiler waits vmcnt on k0r..v1r
        *(short8*)&Ks[kpos][kd + 32] = k1r;
#pragma unroll
        for (int j = 0; j < 8; j++) {
            u32 pk = (u32)(u16)v0r[j] | ((u32)(u16)v1r[j] << 16);
            *(u32*)&Vs[vd + j][2 * p2] = pk;
        }
        if (kt + 1 < S / 64) {            // issue next tile; latency hides
            const int nb = (kt + 1) * 64; // under this tile's compute
            k0r = *(const short8*)&Kh[(size_t)(nb + kpos) * D + kd];
            k1r = *(const short8*)&Kh[(size_t)(nb + kpos) * D + kd + 32];
            v0r = *(const short8*)&Vh[(size_t)(nb + 2 * p2) * D + vd];
            v1r = *(const short8*)&Vh[(size_t)(nb + 2 * p2 + 1) * D + vd];
        }
        asm volatile("s_waitcnt lgkmcnt(0)" ::: "memory");  // LDS writes only
        __builtin_amdgcn_s_barrier();
        asm volatile("" ::: "memory");

        const int kbase = kt * 64;

        // ---- QK^T ----
        f32x4 s_acc[4];
#pragma unroll
        for (int ni = 0; ni < 4; ni++) s_acc[ni] = zero4();
        __builtin_amdgcn_s_setprio(1);
#pragma unroll
        for (int ni = 0; ni < 4; ni++) {
            short8 bk0 = *(const short8*)&Ks[ni * 16 + c][quad * 8];
            short8 bk1 = *(const short8*)&Ks[ni * 16 + c][32 + quad * 8];
            s_acc[ni] = __builtin_amdgcn_mfma_f32_16x16x32_bf16(aq0, bk0, s_acc[ni], 0, 0, 0);
            s_acc[ni] = __builtin_amdgcn_mfma_f32_16x16x32_bf16(aq1, bk1, s_acc[ni], 0, 0, 0);
        }
        __builtin_amdgcn_s_setprio(0);

        // ---- softmax + paired P pack/store ----
        // lane(c even) packs rows quad*4+{0,1}; lane(c odd) rows quad*4+{2,3};
        // each u32 = bf16 P[q][k_even] | P[q][k_even+1]<<16 at &Ps[q][k_even].
        // Result layout identical to R11's scalar stores; 8 u32 writes at
        // bank (16q + 4rsel + 8ni + c/2): 2-way max (free, m136).
#pragma unroll
        for (int ni = 0; ni < 4; ni++) {
            const float bias = b2f(msb[kbase + ni * 16 + c]);
            float p0 = __expf(fmaf(s_acc[ni][0], 0.125f, bias));
            float p1 = __expf(fmaf(s_acc[ni][1], 0.125f, bias));
            float p2f = __expf(fmaf(s_acc[ni][2], 0.125f, bias));
            float p3 = __expf(fmaf(s_acc[ni][3], 0.125f, bias));
            l_r[0] += p0; l_r[1] += p1; l_r[2] += p2f; l_r[3] += p3;
            const float t0 = __shfl_xor(p0, 1);
            const float t1 = __shfl_xor(p1, 1);
            const float t2 = __shfl_xor(p2f, 1);
            const float t3 = __shfl_xor(p3, 1);
            const bool ev = (lane & 1) == 0;
            const u32 w0 = ev ? cvtpk(p0, t0) : cvtpk(t2, p2f);
            const u32 w1 = ev ? cvtpk(p1, t1) : cvtpk(t3, p3);
            const int rA = quad * 4 + (ev ? 0 : 2);
            const int colE = ni * 16 + (c & ~1);
            *(u32*)&Ps[w][rA][colE] = w0;
            *(u32*)&Ps[w][rA + 1][colE] = w1;
        }
        // Ps is per-wave: in-order DS pipeline orders stores before our reads.

        short8 ap0 = *(const short8*)&Ps[w][c][quad * 8];
        short8 ap1 = *(const short8*)&Ps[w][c][32 + quad * 8];
        __builtin_amdgcn_s_setprio(1);
#pragma unroll
        for (int ni = 0; ni < 4; ni++) {
            union { short8 v8; s16x4 v4[2]; } u0, u1;
            u0.v4[0] = *(const s16x4*)&Vs[ni * 16 + c][quad * 8];
            u0.v4[1] = *(const s16x4*)&Vs[ni * 16 + c][quad * 8 + 4];
            u1.v4[0] = *(const s16x4*)&Vs[ni * 16 + c][32 + quad * 8];
            u1.v4[1] = *(const s16x4*)&Vs[ni * 16 + c][32 + quad * 8 + 4];
            o_acc[ni] = __builtin_amdgcn_mfma_f32_16x16x32_bf16(ap0, u0.v8, o_acc[ni], 0, 0, 0);
            o_acc[ni] = __builtin_amdgcn_mfma_f32_16x16x32_bf16(ap1, u1.v8, o_acc[ni], 0, 0, 0);
        }
        __builtin_amdgcn_s_setprio(0);
    }

#pragma unroll
    for (int r = 0; r < 4; r++) {
#pragma unroll
        for (int off = 8; off; off >>= 1)
            l_r[r] += __shfl_xor(l_r[r], off, 16);
    }

    const size_t ybase = ((size_t)b * S) * 768 + h * 64;
#pragma unroll
    for (int r = 0; r < 4; r++) {
        const float inv = 1.f / fmaxf(l_r[r], 1e-30f);
        const int srow = qt * 64 + w * 16 + quad * 4 + r;
#pragma unroll
        for (int ni = 0; ni < 4; ni++)
            Y[ybase + (size_t)srow * 768 + ni * 16 + c] = f2b(o_acc[ni][r] * inv);
    }
}

extern "C" void kernel_launch(void* const* d_in, const int* in_sizes, int n_in,
                              void* d_out, int out_size, void* d_ws, size_t ws_size,
                              hipStream_t stream) {
    const float* x     = (const float*)d_in[0];
    const int* attmask = (const int*)d_in[1];
    const float* Wqkv  = (const float*)d_in[2];
    const float* bqkv  = (const float*)d_in[3];
    const float* Wproj = (const float*)d_in[4];
    const float* bproj = (const float*)d_in[5];
    float* outf = (float*)d_out;

    // ws layout: bf16 staging + intermediates (all fully rewritten per launch)
    u16* base = (u16*)d_ws;
    const size_t nx = 4ull * 2048 * 768;       // 6,291,456
    const size_t nwqkv = 768ull * 2304;        // 1,769,472
    const size_t nwproj = 768ull * 768;        // 589,824
    u16* xb     = base;
    u16* Wqkvb  = xb + nx;
    u16* Wprojb = Wqkvb + nwqkv;
    u16* Qb     = Wprojb + nwproj;
    const size_t headElems = 48ull * 2048 * 64;  // 6,291,456
    u16* Kb = Qb + headElems;
    u16* Vb = Kb + headElems;
    u16* Yb = Vb + headElems;

    auto conv = [&](const float* src, u16* dst, size_t n) {
        int n8 = (int)(n / 8);
        int blocks = (n8 + 255) / 256;
        if (blocks > 1024) blocks = 1024;
        convert_kernel<<<blocks, 256, 0, stream>>>(src, dst, n8);
    };
    conv(x, xb, nx);
    conv(Wqkv, Wqkvb, nwqkv);
    conv(Wproj, Wprojb, nwproj);

    // QKV GEMM: [8192,768]x[768,2304] + bias -> Q/K/V [b,h,s,d] bf16
    gemm_bias_kernel<0><<<dim3(18, 64), 256, 0, stream>>>(
        xb, Wqkvb, bqkv, Qb, Kb, Vb, nullptr, 8192, 2304, 768);
    // Flash attention -> Y [b,s,768] bf16
    attn_kernel<<<dim3(48, 32), 256, 0, stream>>>(Qb, Kb, Vb, attmask, Yb);
    // Proj GEMM: [8192,768]x[768,768] + bias -> d_out fp32
    gemm_bias_kernel<1><<<dim3(6, 64), 256, 0, stream>>>(
        Yb, Wprojb, bproj, nullptr, nullptr, nullptr, outf, 8192, 768, 768);
}

// Round 3
// 298.867 us; speedup vs baseline: 1.0620x; 1.0620x over previous
//
#include <hip/hip_runtime.h>

typedef unsigned short u16;
typedef unsigned int u32;
typedef __attribute__((ext_vector_type(8))) short short8;
typedef __attribute__((ext_vector_type(4))) short s16x4;
typedef __attribute__((ext_vector_type(4))) float f32x4;

__device__ __forceinline__ float b2f(u16 u) {
    union { u32 i; float f; } v; v.i = ((u32)u) << 16; return v.f;
}
__device__ __forceinline__ u16 f2b(float f) {
    union { u32 i; float f; } v; v.f = f;
    u32 u = v.i;
    return (u16)((u + 0x7FFFu + ((u >> 16) & 1u)) >> 16);
}
__device__ __forceinline__ f32x4 zero4() {
    f32x4 v; v[0] = 0.f; v[1] = 0.f; v[2] = 0.f; v[3] = 0.f; return v;
}

// ---------------------------------------------------------------------------
// fp32 -> bf16 convert (one-time staging; 33 MB total ~ 10us at HBM rate).
// ---------------------------------------------------------------------------
__global__ void convert_kernel(const float* __restrict__ src, u16* __restrict__ dst,
                               int n8) {
    const int stride = gridDim.x * blockDim.x;
    for (int i = blockIdx.x * blockDim.x + threadIdx.x; i < n8; i += stride) {
        const float* s = src + (size_t)i * 8;
        float4 a = ((const float4*)s)[0];
        float4 b = ((const float4*)s)[1];
        short8 o;
        o[0] = (short)f2b(a.x); o[1] = (short)f2b(a.y);
        o[2] = (short)f2b(a.z); o[3] = (short)f2b(a.w);
        o[4] = (short)f2b(b.x); o[5] = (short)f2b(b.y);
        o[6] = (short)f2b(b.z); o[7] = (short)f2b(b.w);
        ((short8*)dst)[i] = o;
    }
}

// ---------------------------------------------------------------------------
// Tiled bf16 MFMA GEMM: C = A[M,K] x B[K,N] + bias[N]; A,B bf16; bias fp32.
// 128x128 tile, BK=32, 4 waves x 4x4 frags of 16x16x32.
// MODE 0: scatter bf16 into Q/K/V [b,h,s,d]. MODE 1: fp32 store to Of [M,N].
// XCD swizzle (T1), verified R13: nwg = 1152 / 384, both % 8 == 0; bijective.
// ---------------------------------------------------------------------------
template <int MODE>
__global__ __launch_bounds__(256, 2) void gemm_bias_kernel(
    const u16* __restrict__ A, const u16* __restrict__ B,
    const float* __restrict__ bias,
    u16* __restrict__ O0, u16* __restrict__ O1, u16* __restrict__ O2,
    float* __restrict__ Of,
    int M, int N, int K)
{
    __shared__ u16 As[128][40];   // [m][k]
    __shared__ u16 Bs[128][36];   // [n][k] transposed

    const int tid = threadIdx.x;
    const int nwgx = gridDim.x;
    const int nwg = nwgx * gridDim.y;
    int lin = blockIdx.y * nwgx + blockIdx.x;
    lin = (lin & 7) * (nwg >> 3) + (lin >> 3);   // bijective: nwg % 8 == 0
    const int m0 = (lin / nwgx) * 128, n0 = (lin % nwgx) * 128;
    const int lane = tid & 63, w = tid >> 6;
    const int quad = lane >> 4, c = lane & 15;
    const int wm = (w & 1) * 64, wn = (w >> 1) * 64;

    f32x4 acc[4][4];
#pragma unroll
    for (int i = 0; i < 4; i++)
#pragma unroll
        for (int j = 0; j < 4; j++) acc[i][j] = zero4();

    const int arow = tid >> 2, acol = (tid & 3) * 8;  // A: 128 rows x 32 k
    const int kp = tid >> 4;                          // B: k-pair 0..15
    const int bnc = (tid & 15) * 8;                   // B: n-group

    for (int k0 = 0; k0 < K; k0 += 32) {
        short8 a0 = *(const short8*)(A + (size_t)(m0 + arow) * K + k0 + acol);
        short8 a1 = *(const short8*)(A + (size_t)(m0 + arow + 64) * K + k0 + acol);
        short8 bl0 = *(const short8*)(B + (size_t)(k0 + 2 * kp) * N + n0 + bnc);
        short8 bl1 = *(const short8*)(B + (size_t)(k0 + 2 * kp + 1) * N + n0 + bnc);

        __syncthreads();  // previous iteration's frag reads done
        *(short8*)&As[arow][acol] = a0;
        *(short8*)&As[arow + 64][acol] = a1;
#pragma unroll
        for (int j = 0; j < 8; j++) {
            u32 pk = (u32)(u16)bl0[j] | ((u32)(u16)bl1[j] << 16);
            *(u32*)&Bs[bnc + j][2 * kp] = pk;
        }
        __syncthreads();

        short8 af[4], bfr[4];
#pragma unroll
        for (int mi = 0; mi < 4; mi++)
            af[mi] = *(const short8*)&As[wm + mi * 16 + c][quad * 8];
#pragma unroll
        for (int ni = 0; ni < 4; ni++) {
            union { short8 v8; s16x4 v4[2]; } u;
            u.v4[0] = *(const s16x4*)&Bs[wn + ni * 16 + c][quad * 8];
            u.v4[1] = *(const s16x4*)&Bs[wn + ni * 16 + c][quad * 8 + 4];
            bfr[ni] = u.v8;
        }
#pragma unroll
        for (int mi = 0; mi < 4; mi++)
#pragma unroll
            for (int ni = 0; ni < 4; ni++)
                acc[mi][ni] = __builtin_amdgcn_mfma_f32_16x16x32_bf16(
                    af[mi], bfr[ni], acc[mi][ni], 0, 0, 0);
    }

#pragma unroll
    for (int ni = 0; ni < 4; ni++) {
        const int gc = n0 + wn + ni * 16 + c;
        const float bv = bias[gc];
        if (MODE == 0) {
            const int which = gc / 768;
            const int e = gc - which * 768;
            const int hh = e >> 6, d = e & 63;
            u16* op = (which == 0) ? O0 : (which == 1 ? O1 : O2);
#pragma unroll
            for (int mi = 0; mi < 4; mi++)
#pragma unroll
                for (int r = 0; r < 4; r++) {
                    const int gr = m0 + wm + mi * 16 + quad * 4 + r;
                    const int bb = gr >> 11, s = gr & 2047;
                    op[(((size_t)bb * 12 + hh) * 2048 + s) * 64 + d] =
                        f2b(acc[mi][ni][r] + bv);
                }
        } else {
#pragma unroll
            for (int mi = 0; mi < 4; mi++)
#pragma unroll
                for (int r = 0; r < 4; r++) {
                    const int gr = m0 + wm + mi * 16 + quad * 4 + r;
                    Of[(size_t)gr * N + gc] = acc[mi][ni][r] + bv;
                }
        }
    }
}

// ---------------------------------------------------------------------------
// Flash attention, KB=64, NO-MAX softmax (scores ~30 sigma below overflow;
// masked -> additive bf16(-29952) bias -> exp underflows to exact 0).
// R14 = R13 minus the shfl P-repack (which serialized the softmax path and
// cost +16 VGPR; counters showed conflicts UNCHANGED at 2.045e7 -> P-write
// was never the conflict source; counter is benign 2-way b128 aliasing, cf.
// m98 GEMM 1.7e7 at 912 TF). Kept from R13 (all verified correct):
//   - T14 prefetch: next K/V tile loads issued right after this tile's LDS
//     writes; raw s_barrier + lgkmcnt(0)-only sync keeps them in flight ->
//     removes ~500-900cy exposed vmcnt wait per tile (the real latency hole).
//   - whole-sequence mask bias msb[2048] -> no per-tile attmask global load.
//   - T5 setprio(1) around MFMA clusters.
// P-write: R11-verbatim 16 scalar f2b stores (known-good 137us path).
// grid (48, 32): head fastest -> XCD-pinned K/V (3 MB / L2).
// ---------------------------------------------------------------------------
__global__ __launch_bounds__(256) void attn_kernel(
    const u16* __restrict__ Q, const u16* __restrict__ Kv,
    const u16* __restrict__ Vv, const int* __restrict__ attmask,
    u16* __restrict__ Y)
{
    const int S = 2048, D = 64, NH = 12;
    __shared__ u16 Ks[64][72];        // [pos][d]
    __shared__ u16 Vs[64][68];        // [d][pos]
    __shared__ u16 Ps[4][16][72];     // per-wave P: [qrow][pos]
    __shared__ u16 msb[2048];         // bf16 additive bias: 0 or -29952

    const int tid = threadIdx.x;
    const int w = tid >> 6, lane = tid & 63;
    const int quad = lane >> 4, c = lane & 15;
    const int bh = blockIdx.x;        // 0..47
    const int qt = blockIdx.y;        // 0..31
    const int b = bh / NH, h = bh - b * NH;

    const u16* Qh = Q + (size_t)bh * S * D;
    const u16* Kh = Kv + (size_t)bh * S * D;
    const u16* Vh = Vv + (size_t)bh * S * D;
    const int q0 = qt * 64 + w * 16;

    short8 aq0 = *(const short8*)&Qh[(size_t)(q0 + c) * D + quad * 8];
    short8 aq1 = *(const short8*)&Qh[(size_t)(q0 + c) * D + 32 + quad * 8];

    // whole-sequence mask bias, staged once (bf16 -29952 = 0xC6EA;
    // exp underflows to exactly 0, matching cndmask-to-zero semantics)
    for (int i = tid; i < S; i += 256)
        msb[i] = (attmask[b * S + i] == 0) ? (u16)0xC6EA : (u16)0;

    f32x4 o_acc[4];
#pragma unroll
    for (int i = 0; i < 4; i++) o_acc[i] = zero4();
    float l_r[4] = {0.f, 0.f, 0.f, 0.f};

    const int kpos = tid >> 2, kd = (tid & 3) * 8;
    const int p2 = tid >> 3, vd = (tid & 7) * 8;

    // T14 prologue: issue tile-0 loads
    short8 k0r = *(const short8*)&Kh[(size_t)kpos * D + kd];
    short8 k1r = *(const short8*)&Kh[(size_t)kpos * D + kd + 32];
    short8 v0r = *(const short8*)&Vh[(size_t)(2 * p2) * D + vd];
    short8 v1r = *(const short8*)&Vh[(size_t)(2 * p2 + 1) * D + vd];

    for (int kt = 0; kt < S / 64; kt++) {
        // ---- staging (raw barriers: vmcnt NOT drained -> prefetch in flight)
        asm volatile("" ::: "memory");
        __builtin_amdgcn_s_barrier();     // prev tile's LDS reads all retired
        asm volatile("" ::: "memory");
        *(short8*)&Ks[kpos][kd] = k0r;    // compiler waits vmcnt on k0r..v1r
        *(short8*)&Ks[kpos][kd + 32] = k1r;
#pragma unroll
        for (int j = 0; j < 8; j++) {
            u32 pk = (u32)(u16)v0r[j] | ((u32)(u16)v1r[j] << 16);
            *(u32*)&Vs[vd + j][2 * p2] = pk;
        }
        if (kt + 1 < S / 64) {            // issue next tile; latency hides
            const int nb = (kt + 1) * 64; // under this tile's compute
            k0r = *(const short8*)&Kh[(size_t)(nb + kpos) * D + kd];
            k1r = *(const short8*)&Kh[(size_t)(nb + kpos) * D + kd + 32];
            v0r = *(const short8*)&Vh[(size_t)(nb + 2 * p2) * D + vd];
            v1r = *(const short8*)&Vh[(size_t)(nb + 2 * p2 + 1) * D + vd];
        }
        asm volatile("s_waitcnt lgkmcnt(0)" ::: "memory");  // LDS writes only
        __builtin_amdgcn_s_barrier();
        asm volatile("" ::: "memory");

        const int kbase = kt * 64;

        // ---- QK^T ----
        f32x4 s_acc[4];
#pragma unroll
        for (int ni = 0; ni < 4; ni++) s_acc[ni] = zero4();
        __builtin_amdgcn_s_setprio(1);
#pragma unroll
        for (int ni = 0; ni < 4; ni++) {
            short8 bk0 = *(const short8*)&Ks[ni * 16 + c][quad * 8];
            short8 bk1 = *(const short8*)&Ks[ni * 16 + c][32 + quad * 8];
            s_acc[ni] = __builtin_amdgcn_mfma_f32_16x16x32_bf16(aq0, bk0, s_acc[ni], 0, 0, 0);
            s_acc[ni] = __builtin_amdgcn_mfma_f32_16x16x32_bf16(aq1, bk1, s_acc[ni], 0, 0, 0);
        }
        __builtin_amdgcn_s_setprio(0);

        // ---- softmax + P store (R11-verbatim scalar path, known-good) ----
#pragma unroll
        for (int ni = 0; ni < 4; ni++) {
            const float bias = b2f(msb[kbase + ni * 16 + c]);
            float p0 = __expf(fmaf(s_acc[ni][0], 0.125f, bias));
            float p1 = __expf(fmaf(s_acc[ni][1], 0.125f, bias));
            float p2f = __expf(fmaf(s_acc[ni][2], 0.125f, bias));
            float p3 = __expf(fmaf(s_acc[ni][3], 0.125f, bias));
            l_r[0] += p0; l_r[1] += p1; l_r[2] += p2f; l_r[3] += p3;
            Ps[w][quad * 4 + 0][ni * 16 + c] = f2b(p0);
            Ps[w][quad * 4 + 1][ni * 16 + c] = f2b(p1);
            Ps[w][quad * 4 + 2][ni * 16 + c] = f2b(p2f);
            Ps[w][quad * 4 + 3][ni * 16 + c] = f2b(p3);
        }
        // Ps is per-wave: in-order DS pipeline orders stores before our reads.

        short8 ap0 = *(const short8*)&Ps[w][c][quad * 8];
        short8 ap1 = *(const short8*)&Ps[w][c][32 + quad * 8];
        __builtin_amdgcn_s_setprio(1);
#pragma unroll
        for (int ni = 0; ni < 4; ni++) {
            union { short8 v8; s16x4 v4[2]; } u0, u1;
            u0.v4[0] = *(const s16x4*)&Vs[ni * 16 + c][quad * 8];
            u0.v4[1] = *(const s16x4*)&Vs[ni * 16 + c][quad * 8 + 4];
            u1.v4[0] = *(const s16x4*)&Vs[ni * 16 + c][32 + quad * 8];
            u1.v4[1] = *(const s16x4*)&Vs[ni * 16 + c][32 + quad * 8 + 4];
            o_acc[ni] = __builtin_amdgcn_mfma_f32_16x16x32_bf16(ap0, u0.v8, o_acc[ni], 0, 0, 0);
            o_acc[ni] = __builtin_amdgcn_mfma_f32_16x16x32_bf16(ap1, u1.v8, o_acc[ni], 0, 0, 0);
        }
        __builtin_amdgcn_s_setprio(0);
    }

#pragma unroll
    for (int r = 0; r < 4; r++) {
#pragma unroll
        for (int off = 8; off; off >>= 1)
            l_r[r] += __shfl_xor(l_r[r], off, 16);
    }

    const size_t ybase = ((size_t)b * S) * 768 + h * 64;
#pragma unroll
    for (int r = 0; r < 4; r++) {
        const float inv = 1.f / fmaxf(l_r[r], 1e-30f);
        const int srow = qt * 64 + w * 16 + quad * 4 + r;
#pragma unroll
        for (int ni = 0; ni < 4; ni++)
            Y[ybase + (size_t)srow * 768 + ni * 16 + c] = f2b(o_acc[ni][r] * inv);
    }
}

extern "C" void kernel_launch(void* const* d_in, const int* in_sizes, int n_in,
                              void* d_out, int out_size, void* d_ws, size_t ws_size,
                              hipStream_t stream) {
    const float* x     = (const float*)d_in[0];
    const int* attmask = (const int*)d_in[1];
    const float* Wqkv  = (const float*)d_in[2];
    const float* bqkv  = (const float*)d_in[3];
    const float* Wproj = (const float*)d_in[4];
    const float* bproj = (const float*)d_in[5];
    float* outf = (float*)d_out;

    // ws layout: bf16 staging + intermediates (all fully rewritten per launch)
    u16* base = (u16*)d_ws;
    const size_t nx = 4ull * 2048 * 768;       // 6,291,456
    const size_t nwqkv = 768ull * 2304;        // 1,769,472
    const size_t nwproj = 768ull * 768;        // 589,824
    u16* xb     = base;
    u16* Wqkvb  = xb + nx;
    u16* Wprojb = Wqkvb + nwqkv;
    u16* Qb     = Wprojb + nwproj;
    const size_t headElems = 48ull * 2048 * 64;  // 6,291,456
    u16* Kb = Qb + headElems;
    u16* Vb = Kb + headElems;
    u16* Yb = Vb + headElems;

    auto conv = [&](const float* src, u16* dst, size_t n) {
        int n8 = (int)(n / 8);
        int blocks = (n8 + 255) / 256;
        if (blocks > 1024) blocks = 1024;
        convert_kernel<<<blocks, 256, 0, stream>>>(src, dst, n8);
    };
    conv(x, xb, nx);
    conv(Wqkv, Wqkvb, nwqkv);
    conv(Wproj, Wprojb, nwproj);

    // QKV GEMM: [8192,768]x[768,2304] + bias -> Q/K/V [b,h,s,d] bf16
    gemm_bias_kernel<0><<<dim3(18, 64), 256, 0, stream>>>(
        xb, Wqkvb, bqkv, Qb, Kb, Vb, nullptr, 8192, 2304, 768);
    // Flash attention -> Y [b,s,768] bf16
    attn_kernel<<<dim3(48, 32), 256, 0, stream>>>(Qb, Kb, Vb, attmask, Yb);
    // Proj GEMM: [8192,768]x[768,768] + bias -> d_out fp32
    gemm_bias_kernel<1><<<dim3(6, 64), 256, 0, stream>>>(
        Yb, Wprojb, bproj, nullptr, nullptr, nullptr, outf, 8192, 768, 768);
}

// Round 4
// 286.648 us; speedup vs baseline: 1.1073x; 1.0426x over previous
//
#include <hip/hip_runtime.h>

typedef unsigned short u16;
typedef unsigned int u32;
typedef __attribute__((ext_vector_type(8))) short short8;
typedef __attribute__((ext_vector_type(4))) short s16x4;
typedef __attribute__((ext_vector_type(4))) float f32x4;

__device__ __forceinline__ float b2f(u16 u) {
    union { u32 i; float f; } v; v.i = ((u32)u) << 16; return v.f;
}
__device__ __forceinline__ u16 f2b(float f) {
    union { u32 i; float f; } v; v.f = f;
    u32 u = v.i;
    return (u16)((u + 0x7FFFu + ((u >> 16) & 1u)) >> 16);
}
__device__ __forceinline__ f32x4 zero4() {
    f32x4 v; v[0] = 0.f; v[1] = 0.f; v[2] = 0.f; v[3] = 0.f; return v;
}
// packed f32x2 -> bf16x2 (RNE); low 16 bits = first arg (HW-verified by R13 pass)
__device__ __forceinline__ u32 cvtpk(float lo, float hi) {
    u32 d;
    asm("v_cvt_pk_bf16_f32 %0, %1, %2" : "=v"(d) : "v"(lo), "v"(hi));
    return d;
}
// exp2 (log2-domain exponent); masked bias -43282 underflows to exact 0
__device__ __forceinline__ float fexp2(float x) {
#if __has_builtin(__builtin_amdgcn_exp2f)
    return __builtin_amdgcn_exp2f(x);
#else
    return __expf(x * 0.6931471805599453f);
#endif
}

// ---------------------------------------------------------------------------
// fp32 -> bf16 convert (one-time staging; 33 MB total ~ 10us at HBM rate).
// ---------------------------------------------------------------------------
__global__ void convert_kernel(const float* __restrict__ src, u16* __restrict__ dst,
                               int n8) {
    const int stride = gridDim.x * blockDim.x;
    for (int i = blockIdx.x * blockDim.x + threadIdx.x; i < n8; i += stride) {
        const float* s = src + (size_t)i * 8;
        float4 a = ((const float4*)s)[0];
        float4 b = ((const float4*)s)[1];
        short8 o;
        o[0] = (short)f2b(a.x); o[1] = (short)f2b(a.y);
        o[2] = (short)f2b(a.z); o[3] = (short)f2b(a.w);
        o[4] = (short)f2b(b.x); o[5] = (short)f2b(b.y);
        o[6] = (short)f2b(b.z); o[7] = (short)f2b(b.w);
        ((short8*)dst)[i] = o;
    }
}

// ---------------------------------------------------------------------------
// Tiled bf16 MFMA GEMM: C = A[M,K] x B[K,N] + bias[N]; A,B bf16; bias fp32.
// 128x128 tile, BK=32, 4 waves x 4x4 frags of 16x16x32.
// MODE 0: scatter bf16 into Q/K/V [b,h,s,d]. MODE 1: fp32 store to Of [M,N].
// XCD swizzle (T1), verified R13/R14: nwg = 1152 / 384, both % 8 == 0.
// ---------------------------------------------------------------------------
template <int MODE>
__global__ __launch_bounds__(256, 2) void gemm_bias_kernel(
    const u16* __restrict__ A, const u16* __restrict__ B,
    const float* __restrict__ bias,
    u16* __restrict__ O0, u16* __restrict__ O1, u16* __restrict__ O2,
    float* __restrict__ Of,
    int M, int N, int K)
{
    __shared__ u16 As[128][40];   // [m][k]
    __shared__ u16 Bs[128][36];   // [n][k] transposed

    const int tid = threadIdx.x;
    const int nwgx = gridDim.x;
    const int nwg = nwgx * gridDim.y;
    int lin = blockIdx.y * nwgx + blockIdx.x;
    lin = (lin & 7) * (nwg >> 3) + (lin >> 3);   // bijective: nwg % 8 == 0
    const int m0 = (lin / nwgx) * 128, n0 = (lin % nwgx) * 128;
    const int lane = tid & 63, w = tid >> 6;
    const int quad = lane >> 4, c = lane & 15;
    const int wm = (w & 1) * 64, wn = (w >> 1) * 64;

    f32x4 acc[4][4];
#pragma unroll
    for (int i = 0; i < 4; i++)
#pragma unroll
        for (int j = 0; j < 4; j++) acc[i][j] = zero4();

    const int arow = tid >> 2, acol = (tid & 3) * 8;  // A: 128 rows x 32 k
    const int kp = tid >> 4;                          // B: k-pair 0..15
    const int bnc = (tid & 15) * 8;                   // B: n-group

    for (int k0 = 0; k0 < K; k0 += 32) {
        short8 a0 = *(const short8*)(A + (size_t)(m0 + arow) * K + k0 + acol);
        short8 a1 = *(const short8*)(A + (size_t)(m0 + arow + 64) * K + k0 + acol);
        short8 bl0 = *(const short8*)(B + (size_t)(k0 + 2 * kp) * N + n0 + bnc);
        short8 bl1 = *(const short8*)(B + (size_t)(k0 + 2 * kp + 1) * N + n0 + bnc);

        __syncthreads();  // previous iteration's frag reads done
        *(short8*)&As[arow][acol] = a0;
        *(short8*)&As[arow + 64][acol] = a1;
#pragma unroll
        for (int j = 0; j < 8; j++) {
            u32 pk = (u32)(u16)bl0[j] | ((u32)(u16)bl1[j] << 16);
            *(u32*)&Bs[bnc + j][2 * kp] = pk;
        }
        __syncthreads();

        short8 af[4], bfr[4];
#pragma unroll
        for (int mi = 0; mi < 4; mi++)
            af[mi] = *(const short8*)&As[wm + mi * 16 + c][quad * 8];
#pragma unroll
        for (int ni = 0; ni < 4; ni++) {
            union { short8 v8; s16x4 v4[2]; } u;
            u.v4[0] = *(const s16x4*)&Bs[wn + ni * 16 + c][quad * 8];
            u.v4[1] = *(const s16x4*)&Bs[wn + ni * 16 + c][quad * 8 + 4];
            bfr[ni] = u.v8;
        }
#pragma unroll
        for (int mi = 0; mi < 4; mi++)
#pragma unroll
            for (int ni = 0; ni < 4; ni++)
                acc[mi][ni] = __builtin_amdgcn_mfma_f32_16x16x32_bf16(
                    af[mi], bfr[ni], acc[mi][ni], 0, 0, 0);
    }

#pragma unroll
    for (int ni = 0; ni < 4; ni++) {
        const int gc = n0 + wn + ni * 16 + c;
        const float bv = bias[gc];
        if (MODE == 0) {
            const int which = gc / 768;
            const int e = gc - which * 768;
            const int hh = e >> 6, d = e & 63;
            u16* op = (which == 0) ? O0 : (which == 1 ? O1 : O2);
#pragma unroll
            for (int mi = 0; mi < 4; mi++)
#pragma unroll
                for (int r = 0; r < 4; r++) {
                    const int gr = m0 + wm + mi * 16 + quad * 4 + r;
                    const int bb = gr >> 11, s = gr & 2047;
                    op[(((size_t)bb * 12 + hh) * 2048 + s) * 64 + d] =
                        f2b(acc[mi][ni][r] + bv);
                }
        } else {
#pragma unroll
            for (int mi = 0; mi < 4; mi++)
#pragma unroll
                for (int r = 0; r < 4; r++) {
                    const int gr = m0 + wm + mi * 16 + quad * 4 + r;
                    Of[(size_t)gr * N + gc] = acc[mi][ni][r] + bv;
                }
        }
    }
}

// ---------------------------------------------------------------------------
// Flash attention, KB=64, NO-MAX softmax.
// R15: SWAPPED QK^T (T12's core idea, cheap form). Compute mfma(K_frag,
// Q_frag) — operand swap only, same registers — so C = S[kpos][q]: each
// lane holds 4 k-ADJACENT scores (kpos = ni*16+quad*4+r) for ONE q-row (c).
// Consequences (vs R11/R14's 16 f2b + 16 u16 DS stores, ~80 VALU/tile):
//   - P pack: 8 v_cvt_pk_bf16_f32 + 4 ds_write_b64 into the SAME Ps[q][pos]
//     layout; PV-side ap reads verbatim. No lane exchange needed (R13's 16
//     shfl_xor existed only because the unswapped layout put k across lanes).
//   - mask bias: k-indexed -> one broadcast (same-address, conflict-free)
//     f32x4 LDS read per ni from exp2-domain table (0 / -43282; underflow
//     to exact 0, semantics HW-verified by R13's pass).
//   - exp2 direct (saves __expf's internal mul): p = exp2(fma(s,SC,bias)).
//   - l: lane-local scalar; 2 shfl_xor + 4 shfl redistribute ONCE at end.
// Kept from R14 (verified passing): T14 prefetch + raw-barrier vmcnt-in-
// flight staging, T5 setprio, per-wave Ps (DS in-order, no fence needed).
// grid (48, 32): head fastest -> XCD-pinned K/V (3 MB / L2).
// ---------------------------------------------------------------------------
__global__ __launch_bounds__(256) void attn_kernel(
    const u16* __restrict__ Q, const u16* __restrict__ Kv,
    const u16* __restrict__ Vv, const int* __restrict__ attmask,
    u16* __restrict__ Y)
{
    const int S = 2048, D = 64, NH = 12;
    __shared__ u16 Ks[64][72];        // [pos][d]
    __shared__ u16 Vs[64][68];        // [d][pos]
    __shared__ u16 Ps[4][16][72];     // per-wave P: [qrow][pos]
    __shared__ float msf[2048];       // exp2-domain mask bias: 0 or -43282

    const int tid = threadIdx.x;
    const int w = tid >> 6, lane = tid & 63;
    const int quad = lane >> 4, c = lane & 15;
    const int bh = blockIdx.x;        // 0..47
    const int qt = blockIdx.y;        // 0..31
    const int b = bh / NH, h = bh - b * NH;

    const u16* Qh = Q + (size_t)bh * S * D;
    const u16* Kh = Kv + (size_t)bh * S * D;
    const u16* Vh = Vv + (size_t)bh * S * D;
    const int q0 = qt * 64 + w * 16;

    short8 aq0 = *(const short8*)&Qh[(size_t)(q0 + c) * D + quad * 8];
    short8 aq1 = *(const short8*)&Qh[(size_t)(q0 + c) * D + 32 + quad * 8];

    // whole-sequence mask bias in exp2 domain, staged once
    for (int i = tid; i < S; i += 256)
        msf[i] = (attmask[b * S + i] == 0) ? -43282.0f : 0.0f;

    f32x4 o_acc[4];
#pragma unroll
    for (int i = 0; i < 4; i++) o_acc[i] = zero4();
    float l = 0.f;   // row-sum for q-row c (partial over this lane's kpos set)

    const int kpos = tid >> 2, kd = (tid & 3) * 8;
    const int p2 = tid >> 3, vd = (tid & 7) * 8;

    // T14 prologue: issue tile-0 loads
    short8 k0r = *(const short8*)&Kh[(size_t)kpos * D + kd];
    short8 k1r = *(const short8*)&Kh[(size_t)kpos * D + kd + 32];
    short8 v0r = *(const short8*)&Vh[(size_t)(2 * p2) * D + vd];
    short8 v1r = *(const short8*)&Vh[(size_t)(2 * p2 + 1) * D + vd];

    const float SC = 0.18033688f;  // 0.125 * log2(e)

    for (int kt = 0; kt < S / 64; kt++) {
        // ---- staging (raw barriers: vmcnt NOT drained -> prefetch in flight)
        asm volatile("" ::: "memory");
        __builtin_amdgcn_s_barrier();     // prev tile's LDS reads all retired
        asm volatile("" ::: "memory");
        *(short8*)&Ks[kpos][kd] = k0r;    // compiler waits vmcnt on k0r..v1r
        *(short8*)&Ks[kpos][kd + 32] = k1r;
#pragma unroll
        for (int j = 0; j < 8; j++) {
            u32 pk = (u32)(u16)v0r[j] | ((u32)(u16)v1r[j] << 16);
            *(u32*)&Vs[vd + j][2 * p2] = pk;
        }
        if (kt + 1 < S / 64) {            // issue next tile; latency hides
            const int nb = (kt + 1) * 64; // under this tile's compute
            k0r = *(const short8*)&Kh[(size_t)(nb + kpos) * D + kd];
            k1r = *(const short8*)&Kh[(size_t)(nb + kpos) * D + kd + 32];
            v0r = *(const short8*)&Vh[(size_t)(nb + 2 * p2) * D + vd];
            v1r = *(const short8*)&Vh[(size_t)(nb + 2 * p2 + 1) * D + vd];
        }
        asm volatile("s_waitcnt lgkmcnt(0)" ::: "memory");  // LDS writes only
        __builtin_amdgcn_s_barrier();
        asm volatile("" ::: "memory");

        const int kbase = kt * 64;

        // ---- QK^T, swapped operands: s_acc[ni] = S[kpos=ni*16+quad*4+r][q=c]
        f32x4 s_acc[4];
#pragma unroll
        for (int ni = 0; ni < 4; ni++) s_acc[ni] = zero4();
        __builtin_amdgcn_s_setprio(1);
#pragma unroll
        for (int ni = 0; ni < 4; ni++) {
            short8 bk0 = *(const short8*)&Ks[ni * 16 + c][quad * 8];
            short8 bk1 = *(const short8*)&Ks[ni * 16 + c][32 + quad * 8];
            s_acc[ni] = __builtin_amdgcn_mfma_f32_16x16x32_bf16(bk0, aq0, s_acc[ni], 0, 0, 0);
            s_acc[ni] = __builtin_amdgcn_mfma_f32_16x16x32_bf16(bk1, aq1, s_acc[ni], 0, 0, 0);
        }
        __builtin_amdgcn_s_setprio(0);

        // ---- softmax: k-adjacent regs -> cvtpk pairs + one b64 store per ni
#pragma unroll
        for (int ni = 0; ni < 4; ni++) {
            // bias indexed by kpos; identical across c -> broadcast read (free)
            const f32x4 bias = *(const f32x4*)&msf[kbase + ni * 16 + quad * 4];
            float p0 = fexp2(fmaf(s_acc[ni][0], SC, bias[0]));
            float p1 = fexp2(fmaf(s_acc[ni][1], SC, bias[1]));
            float p2f = fexp2(fmaf(s_acc[ni][2], SC, bias[2]));
            float p3 = fexp2(fmaf(s_acc[ni][3], SC, bias[3]));
            l += (p0 + p1) + (p2f + p3);
            uint2 pk;
            pk.x = cvtpk(p0, p1);
            pk.y = cvtpk(p2f, p3);
            // P[q=c][kpos base ni*16+quad*4], 8B aligned (row stride 144)
            *(uint2*)&Ps[w][c][ni * 16 + quad * 4] = pk;
        }
        // Ps is per-wave: in-order DS pipeline orders stores before our reads.

        short8 ap0 = *(const short8*)&Ps[w][c][quad * 8];
        short8 ap1 = *(const short8*)&Ps[w][c][32 + quad * 8];
        __builtin_amdgcn_s_setprio(1);
#pragma unroll
        for (int ni = 0; ni < 4; ni++) {
            union { short8 v8; s16x4 v4[2]; } u0, u1;
            u0.v4[0] = *(const s16x4*)&Vs[ni * 16 + c][quad * 8];
            u0.v4[1] = *(const s16x4*)&Vs[ni * 16 + c][quad * 8 + 4];
            u1.v4[0] = *(const s16x4*)&Vs[ni * 16 + c][32 + quad * 8];
            u1.v4[1] = *(const s16x4*)&Vs[ni * 16 + c][32 + quad * 8 + 4];
            o_acc[ni] = __builtin_amdgcn_mfma_f32_16x16x32_bf16(ap0, u0.v8, o_acc[ni], 0, 0, 0);
            o_acc[ni] = __builtin_amdgcn_mfma_f32_16x16x32_bf16(ap1, u1.v8, o_acc[ni], 0, 0, 0);
        }
        __builtin_amdgcn_s_setprio(0);
    }

    // full row-sum: quads hold disjoint kpos subsets of row c
    l += __shfl_xor(l, 16);
    l += __shfl_xor(l, 32);

    const size_t ybase = ((size_t)b * S) * 768 + h * 64;
#pragma unroll
    for (int r = 0; r < 4; r++) {
        // o_acc rows are q = quad*4+r; l lives at lane with c = quad*4+r
        const float lr = __shfl(l, quad * 4 + r);
        const float inv = 1.f / fmaxf(lr, 1e-30f);
        const int srow = qt * 64 + w * 16 + quad * 4 + r;
#pragma unroll
        for (int ni = 0; ni < 4; ni++)
            Y[ybase + (size_t)srow * 768 + ni * 16 + c] = f2b(o_acc[ni][r] * inv);
    }
}

extern "C" void kernel_launch(void* const* d_in, const int* in_sizes, int n_in,
                              void* d_out, int out_size, void* d_ws, size_t ws_size,
                              hipStream_t stream) {
    const float* x     = (const float*)d_in[0];
    const int* attmask = (const int*)d_in[1];
    const float* Wqkv  = (const float*)d_in[2];
    const float* bqkv  = (const float*)d_in[3];
    const float* Wproj = (const float*)d_in[4];
    const float* bproj = (const float*)d_in[5];
    float* outf = (float*)d_out;

    // ws layout: bf16 staging + intermediates (all fully rewritten per launch)
    u16* base = (u16*)d_ws;
    const size_t nx = 4ull * 2048 * 768;       // 6,291,456
    const size_t nwqkv = 768ull * 2304;        // 1,769,472
    const size_t nwproj = 768ull * 768;        // 589,824
    u16* xb     = base;
    u16* Wqkvb  = xb + nx;
    u16* Wprojb = Wqkvb + nwqkv;
    u16* Qb     = Wprojb + nwproj;
    const size_t headElems = 48ull * 2048 * 64;  // 6,291,456
    u16* Kb = Qb + headElems;
    u16* Vb = Kb + headElems;
    u16* Yb = Vb + headElems;

    auto conv = [&](const float* src, u16* dst, size_t n) {
        int n8 = (int)(n / 8);
        int blocks = (n8 + 255) / 256;
        if (blocks > 1024) blocks = 1024;
        convert_kernel<<<blocks, 256, 0, stream>>>(src, dst, n8);
    };
    conv(x, xb, nx);
    conv(Wqkv, Wqkvb, nwqkv);
    conv(Wproj, Wprojb, nwproj);

    // QKV GEMM: [8192,768]x[768,2304] + bias -> Q/K/V [b,h,s,d] bf16
    gemm_bias_kernel<0><<<dim3(18, 64), 256, 0, stream>>>(
        xb, Wqkvb, bqkv, Qb, Kb, Vb, nullptr, 8192, 2304, 768);
    // Flash attention -> Y [b,s,768] bf16
    attn_kernel<<<dim3(48, 32), 256, 0, stream>>>(Qb, Kb, Vb, attmask, Yb);
    // Proj GEMM: [8192,768]x[768,768] + bias -> d_out fp32
    gemm_bias_kernel<1><<<dim3(6, 64), 256, 0, stream>>>(
        Yb, Wprojb, bproj, nullptr, nullptr, nullptr, outf, 8192, 768, 768);
}

// Round 5
// 268.366 us; speedup vs baseline: 1.1827x; 1.0681x over previous
//
#include <hip/hip_runtime.h>

typedef unsigned short u16;
typedef unsigned int u32;
typedef __attribute__((ext_vector_type(8))) short short8;
typedef __attribute__((ext_vector_type(4))) short s16x4;
typedef __attribute__((ext_vector_type(4))) float f32x4;

__device__ __forceinline__ float b2f(u16 u) {
    union { u32 i; float f; } v; v.i = ((u32)u) << 16; return v.f;
}
__device__ __forceinline__ u16 f2b(float f) {
    union { u32 i; float f; } v; v.f = f;
    u32 u = v.i;
    return (u16)((u + 0x7FFFu + ((u >> 16) & 1u)) >> 16);
}
__device__ __forceinline__ f32x4 zero4() {
    f32x4 v; v[0] = 0.f; v[1] = 0.f; v[2] = 0.f; v[3] = 0.f; return v;
}
// packed f32x2 -> bf16x2 (RNE); low 16 bits = first arg (HW-verified R13/R15)
__device__ __forceinline__ u32 cvtpk(float lo, float hi) {
    u32 d;
    asm("v_cvt_pk_bf16_f32 %0, %1, %2" : "=v"(d) : "v"(lo), "v"(hi));
    return d;
}
__device__ __forceinline__ float fexp2(float x) {
#if __has_builtin(__builtin_amdgcn_exp2f)
    return __builtin_amdgcn_exp2f(x);
#else
    return __expf(x * 0.6931471805599453f);
#endif
}
// async global->LDS, 16B per lane: lane l's 16B land at ldsbase + l*16.
// Guide §5 / m97: +69% over register staging; compiler never auto-emits.
__device__ __forceinline__ void gload16(const u16* g, u16* l) {
    __builtin_amdgcn_global_load_lds(
        (const __attribute__((address_space(1))) u32*)g,
        (__attribute__((address_space(3))) u32*)l, 16, 0, 0);
}

// ---------------------------------------------------------------------------
// fp32 -> bf16 convert (x only; 37.7 MB traffic ~ 7us).
// ---------------------------------------------------------------------------
__global__ void convert_kernel(const float* __restrict__ src, u16* __restrict__ dst,
                               int n8) {
    const int stride = gridDim.x * blockDim.x;
    for (int i = blockIdx.x * blockDim.x + threadIdx.x; i < n8; i += stride) {
        const float* s = src + (size_t)i * 8;
        float4 a = ((const float4*)s)[0];
        float4 b = ((const float4*)s)[1];
        short8 o;
        o[0] = (short)f2b(a.x); o[1] = (short)f2b(a.y);
        o[2] = (short)f2b(a.z); o[3] = (short)f2b(a.w);
        o[4] = (short)f2b(b.x); o[5] = (short)f2b(b.y);
        o[6] = (short)f2b(b.z); o[7] = (short)f2b(b.w);
        ((short8*)dst)[i] = o;
    }
}

// ---------------------------------------------------------------------------
// fp32 [K][N] -> bf16 [N][K] transpose-convert (weights, one-time, ~9 MB).
// 64x64 LDS tile: coalesced float4 reads, coalesced short8 writes.
// Enables the m97 B^T GEMM structure (global_load_lds needs linear LDS dest,
// which the old in-GEMM transpose pack made impossible).
// ---------------------------------------------------------------------------
__global__ void tconvert_kernel(const float* __restrict__ src, u16* __restrict__ dst,
                                int K, int N) {
    __shared__ u16 T[64][72];
    const int n0 = blockIdx.x * 64, k0 = blockIdx.y * 64;
    const int tid = threadIdx.x;
    const int r = tid >> 3, cq = tid & 7;   // r: 0..31, cq: 0..7
#pragma unroll
    for (int half = 0; half < 2; half++) {
        const int k = k0 + half * 32 + r;
        const float* s = &src[(size_t)k * N + n0 + cq * 8];
        const float4 f0 = ((const float4*)s)[0];
        const float4 f1 = ((const float4*)s)[1];
        T[cq * 8 + 0][half * 32 + r] = f2b(f0.x);
        T[cq * 8 + 1][half * 32 + r] = f2b(f0.y);
        T[cq * 8 + 2][half * 32 + r] = f2b(f0.z);
        T[cq * 8 + 3][half * 32 + r] = f2b(f0.w);
        T[cq * 8 + 4][half * 32 + r] = f2b(f1.x);
        T[cq * 8 + 5][half * 32 + r] = f2b(f1.y);
        T[cq * 8 + 6][half * 32 + r] = f2b(f1.z);
        T[cq * 8 + 7][half * 32 + r] = f2b(f1.w);
    }
    __syncthreads();
#pragma unroll
    for (int half = 0; half < 2; half++) {
        const int n = half * 32 + r;
        short8 o = *(const short8*)&T[n][cq * 8];
        *(short8*)&dst[(size_t)(n0 + n) * K + k0 + cq * 8] = o;
    }
}

// ---------------------------------------------------------------------------
// m97-structure GEMM: C = A[M,K] x Bt[N,K]^T + bias[N]; A,Bt bf16 row-major
// along K. 128x128 tile, BK=32, 4 waves x 4x4 frags of 16x16x32.
// Staging = 4 global_load_lds_dwordx4 per wave per K-step into linear
// [128][32] LDS (ladder step 3: 517->874 TF measured, m97/m193). Zero
// staging VALU. Frag-read math identical to the R15-passing kernel (only the
// row stride changed 40/36 -> 32), so the compute path is provably unchanged.
// Bank-conflict count of this layout is benign (m98: 1.7e7 at 874 TF); T2
// swizzle deliberately NOT applied (regime-gated off at 2-phase, m228d).
// MODE 0: scatter bf16 into Q/K/V [b,h,s,d]. MODE 1: fp32 store to Of [M,N].
// XCD swizzle (T1), verified R13-R15: nwg = 1152 / 384, both % 8 == 0.
// ---------------------------------------------------------------------------
template <int MODE>
__global__ __launch_bounds__(256, 2) void gemm_bt_kernel(
    const u16* __restrict__ A, const u16* __restrict__ Bt,
    const float* __restrict__ bias,
    u16* __restrict__ O0, u16* __restrict__ O1, u16* __restrict__ O2,
    float* __restrict__ Of,
    int M, int N, int K)
{
    __shared__ u16 As[128 * 32];   // [m][k] linear (gload_lds dest: no pad)
    __shared__ u16 Bs[128 * 32];   // [n][k] linear

    const int tid = threadIdx.x;
    const int nwgx = gridDim.x;
    const int nwg = nwgx * gridDim.y;
    int lin = blockIdx.y * nwgx + blockIdx.x;
    lin = (lin & 7) * (nwg >> 3) + (lin >> 3);   // bijective: nwg % 8 == 0
    const int m0 = (lin / nwgx) * 128, n0 = (lin % nwgx) * 128;
    const int lane = tid & 63, w = tid >> 6;
    const int quad = lane >> 4, c = lane & 15;
    const int wm = (w & 1) * 64, wn = (w >> 1) * 64;

    f32x4 acc[4][4];
#pragma unroll
    for (int i = 0; i < 4; i++)
#pragma unroll
        for (int j = 0; j < 4; j++) acc[i][j] = zero4();

    // gload geometry: wave w instr i covers LDS bytes [w*2048 + i*1024) of a
    // [128][32] u16 tile -> rows w*32 + i*16 + (lane>>2), k-cols (lane&3)*8.
    const int grow = w * 32 + (lane >> 2);
    const int gcol = (lane & 3) * 8;
    const size_t abase = (size_t)(m0 + grow) * K + gcol;
    const size_t bbase = (size_t)(n0 + grow) * K + gcol;
    u16* asl = &As[w * 1024];      // wave-uniform LDS base (+512 u16 = +1 KiB)
    u16* bsl = &Bs[w * 1024];

    for (int k0 = 0; k0 < K; k0 += 32) {
        __syncthreads();           // previous iteration's frag reads done
        gload16(A + abase + k0, asl);
        gload16(A + abase + (size_t)16 * K + k0, asl + 512);
        gload16(Bt + bbase + k0, bsl);
        gload16(Bt + bbase + (size_t)16 * K + k0, bsl + 512);
        asm volatile("s_waitcnt vmcnt(0)" ::: "memory");  // tile landed in LDS
        __syncthreads();

        short8 af[4], bfr[4];
#pragma unroll
        for (int mi = 0; mi < 4; mi++)
            af[mi] = *(const short8*)&As[(wm + mi * 16 + c) * 32 + quad * 8];
#pragma unroll
        for (int ni = 0; ni < 4; ni++)
            bfr[ni] = *(const short8*)&Bs[(wn + ni * 16 + c) * 32 + quad * 8];
#pragma unroll
        for (int mi = 0; mi < 4; mi++)
#pragma unroll
            for (int ni = 0; ni < 4; ni++)
                acc[mi][ni] = __builtin_amdgcn_mfma_f32_16x16x32_bf16(
                    af[mi], bfr[ni], acc[mi][ni], 0, 0, 0);
    }

#pragma unroll
    for (int ni = 0; ni < 4; ni++) {
        const int gc = n0 + wn + ni * 16 + c;
        const float bv = bias[gc];
        if (MODE == 0) {
            const int which = gc / 768;
            const int e = gc - which * 768;
            const int hh = e >> 6, d = e & 63;
            u16* op = (which == 0) ? O0 : (which == 1 ? O1 : O2);
#pragma unroll
            for (int mi = 0; mi < 4; mi++)
#pragma unroll
                for (int r = 0; r < 4; r++) {
                    const int gr = m0 + wm + mi * 16 + quad * 4 + r;
                    const int bb = gr >> 11, s = gr & 2047;
                    op[(((size_t)bb * 12 + hh) * 2048 + s) * 64 + d] =
                        f2b(acc[mi][ni][r] + bv);
                }
        } else {
#pragma unroll
            for (int mi = 0; mi < 4; mi++)
#pragma unroll
                for (int r = 0; r < 4; r++) {
                    const int gr = m0 + wm + mi * 16 + quad * 4 + r;
                    Of[(size_t)gr * N + gc] = acc[mi][ni][r] + bv;
                }
        }
    }
}

// ---------------------------------------------------------------------------
// Flash attention — UNCHANGED from R15 (verified passing, 126.2 us):
// swapped QK^T (lane-local P rows), cvtpk+b64 P stores, exp2-domain mask
// bias, T14 prefetch with raw barriers, T5 setprio.
// ---------------------------------------------------------------------------
__global__ __launch_bounds__(256) void attn_kernel(
    const u16* __restrict__ Q, const u16* __restrict__ Kv,
    const u16* __restrict__ Vv, const int* __restrict__ attmask,
    u16* __restrict__ Y)
{
    const int S = 2048, D = 64, NH = 12;
    __shared__ u16 Ks[64][72];        // [pos][d]
    __shared__ u16 Vs[64][68];        // [d][pos]
    __shared__ u16 Ps[4][16][72];     // per-wave P: [qrow][pos]
    __shared__ float msf[2048];       // exp2-domain mask bias: 0 or -43282

    const int tid = threadIdx.x;
    const int w = tid >> 6, lane = tid & 63;
    const int quad = lane >> 4, c = lane & 15;
    const int bh = blockIdx.x;        // 0..47
    const int qt = blockIdx.y;        // 0..31
    const int b = bh / NH, h = bh - b * NH;

    const u16* Qh = Q + (size_t)bh * S * D;
    const u16* Kh = Kv + (size_t)bh * S * D;
    const u16* Vh = Vv + (size_t)bh * S * D;
    const int q0 = qt * 64 + w * 16;

    short8 aq0 = *(const short8*)&Qh[(size_t)(q0 + c) * D + quad * 8];
    short8 aq1 = *(const short8*)&Qh[(size_t)(q0 + c) * D + 32 + quad * 8];

    for (int i = tid; i < S; i += 256)
        msf[i] = (attmask[b * S + i] == 0) ? -43282.0f : 0.0f;

    f32x4 o_acc[4];
#pragma unroll
    for (int i = 0; i < 4; i++) o_acc[i] = zero4();
    float l = 0.f;

    const int kpos = tid >> 2, kd = (tid & 3) * 8;
    const int p2 = tid >> 3, vd = (tid & 7) * 8;

    short8 k0r = *(const short8*)&Kh[(size_t)kpos * D + kd];
    short8 k1r = *(const short8*)&Kh[(size_t)kpos * D + kd + 32];
    short8 v0r = *(const short8*)&Vh[(size_t)(2 * p2) * D + vd];
    short8 v1r = *(const short8*)&Vh[(size_t)(2 * p2 + 1) * D + vd];

    const float SC = 0.18033688f;  // 0.125 * log2(e)

    for (int kt = 0; kt < S / 64; kt++) {
        asm volatile("" ::: "memory");
        __builtin_amdgcn_s_barrier();
        asm volatile("" ::: "memory");
        *(short8*)&Ks[kpos][kd] = k0r;
        *(short8*)&Ks[kpos][kd + 32] = k1r;
#pragma unroll
        for (int j = 0; j < 8; j++) {
            u32 pk = (u32)(u16)v0r[j] | ((u32)(u16)v1r[j] << 16);
            *(u32*)&Vs[vd + j][2 * p2] = pk;
        }
        if (kt + 1 < S / 64) {
            const int nb = (kt + 1) * 64;
            k0r = *(const short8*)&Kh[(size_t)(nb + kpos) * D + kd];
            k1r = *(const short8*)&Kh[(size_t)(nb + kpos) * D + kd + 32];
            v0r = *(const short8*)&Vh[(size_t)(nb + 2 * p2) * D + vd];
            v1r = *(const short8*)&Vh[(size_t)(nb + 2 * p2 + 1) * D + vd];
        }
        asm volatile("s_waitcnt lgkmcnt(0)" ::: "memory");
        __builtin_amdgcn_s_barrier();
        asm volatile("" ::: "memory");

        const int kbase = kt * 64;

        f32x4 s_acc[4];
#pragma unroll
        for (int ni = 0; ni < 4; ni++) s_acc[ni] = zero4();
        __builtin_amdgcn_s_setprio(1);
#pragma unroll
        for (int ni = 0; ni < 4; ni++) {
            short8 bk0 = *(const short8*)&Ks[ni * 16 + c][quad * 8];
            short8 bk1 = *(const short8*)&Ks[ni * 16 + c][32 + quad * 8];
            s_acc[ni] = __builtin_amdgcn_mfma_f32_16x16x32_bf16(bk0, aq0, s_acc[ni], 0, 0, 0);
            s_acc[ni] = __builtin_amdgcn_mfma_f32_16x16x32_bf16(bk1, aq1, s_acc[ni], 0, 0, 0);
        }
        __builtin_amdgcn_s_setprio(0);

#pragma unroll
        for (int ni = 0; ni < 4; ni++) {
            const f32x4 bias = *(const f32x4*)&msf[kbase + ni * 16 + quad * 4];
            float p0 = fexp2(fmaf(s_acc[ni][0], SC, bias[0]));
            float p1 = fexp2(fmaf(s_acc[ni][1], SC, bias[1]));
            float p2f = fexp2(fmaf(s_acc[ni][2], SC, bias[2]));
            float p3 = fexp2(fmaf(s_acc[ni][3], SC, bias[3]));
            l += (p0 + p1) + (p2f + p3);
            uint2 pk;
            pk.x = cvtpk(p0, p1);
            pk.y = cvtpk(p2f, p3);
            *(uint2*)&Ps[w][c][ni * 16 + quad * 4] = pk;
        }

        short8 ap0 = *(const short8*)&Ps[w][c][quad * 8];
        short8 ap1 = *(const short8*)&Ps[w][c][32 + quad * 8];
        __builtin_amdgcn_s_setprio(1);
#pragma unroll
        for (int ni = 0; ni < 4; ni++) {
            union { short8 v8; s16x4 v4[2]; } u0, u1;
            u0.v4[0] = *(const s16x4*)&Vs[ni * 16 + c][quad * 8];
            u0.v4[1] = *(const s16x4*)&Vs[ni * 16 + c][quad * 8 + 4];
            u1.v4[0] = *(const s16x4*)&Vs[ni * 16 + c][32 + quad * 8];
            u1.v4[1] = *(const s16x4*)&Vs[ni * 16 + c][32 + quad * 8 + 4];
            o_acc[ni] = __builtin_amdgcn_mfma_f32_16x16x32_bf16(ap0, u0.v8, o_acc[ni], 0, 0, 0);
            o_acc[ni] = __builtin_amdgcn_mfma_f32_16x16x32_bf16(ap1, u1.v8, o_acc[ni], 0, 0, 0);
        }
        __builtin_amdgcn_s_setprio(0);
    }

    l += __shfl_xor(l, 16);
    l += __shfl_xor(l, 32);

    const size_t ybase = ((size_t)b * S) * 768 + h * 64;
#pragma unroll
    for (int r = 0; r < 4; r++) {
        const float lr = __shfl(l, quad * 4 + r);
        const float inv = 1.f / fmaxf(lr, 1e-30f);
        const int srow = qt * 64 + w * 16 + quad * 4 + r;
#pragma unroll
        for (int ni = 0; ni < 4; ni++)
            Y[ybase + (size_t)srow * 768 + ni * 16 + c] = f2b(o_acc[ni][r] * inv);
    }
}

extern "C" void kernel_launch(void* const* d_in, const int* in_sizes, int n_in,
                              void* d_out, int out_size, void* d_ws, size_t ws_size,
                              hipStream_t stream) {
    const float* x     = (const float*)d_in[0];
    const int* attmask = (const int*)d_in[1];
    const float* Wqkv  = (const float*)d_in[2];
    const float* bqkv  = (const float*)d_in[3];
    const float* Wproj = (const float*)d_in[4];
    const float* bproj = (const float*)d_in[5];
    float* outf = (float*)d_out;

    // ws layout: bf16 staging + intermediates (all fully rewritten per launch)
    u16* base = (u16*)d_ws;
    const size_t nx = 4ull * 2048 * 768;       // 6,291,456
    const size_t nwqkv = 768ull * 2304;        // 1,769,472
    const size_t nwproj = 768ull * 768;        // 589,824
    u16* xb     = base;
    u16* Wqkvb  = xb + nx;          // TRANSPOSED: [2304][768]
    u16* Wprojb = Wqkvb + nwqkv;    // TRANSPOSED: [768][768]
    u16* Qb     = Wprojb + nwproj;
    const size_t headElems = 48ull * 2048 * 64;  // 6,291,456
    u16* Kb = Qb + headElems;
    u16* Vb = Kb + headElems;
    u16* Yb = Vb + headElems;

    {
        int n8 = (int)(nx / 8);
        int blocks = (n8 + 255) / 256;
        if (blocks > 1024) blocks = 1024;
        convert_kernel<<<blocks, 256, 0, stream>>>(x, xb, n8);
    }
    // weights: fp32 [K][N] -> bf16 [N][K] (transpose-convert, one-time)
    tconvert_kernel<<<dim3(2304 / 64, 768 / 64), 256, 0, stream>>>(Wqkv, Wqkvb, 768, 2304);
    tconvert_kernel<<<dim3(768 / 64, 768 / 64), 256, 0, stream>>>(Wproj, Wprojb, 768, 768);

    // QKV GEMM: [8192,768] x [2304,768]^T + bias -> Q/K/V [b,h,s,d] bf16
    gemm_bt_kernel<0><<<dim3(18, 64), 256, 0, stream>>>(
        xb, Wqkvb, bqkv, Qb, Kb, Vb, nullptr, 8192, 2304, 768);
    // Flash attention -> Y [b,s,768] bf16
    attn_kernel<<<dim3(48, 32), 256, 0, stream>>>(Qb, Kb, Vb, attmask, Yb);
    // Proj GEMM: [8192,768] x [768,768]^T + bias -> d_out fp32
    gemm_bt_kernel<1><<<dim3(6, 64), 256, 0, stream>>>(
        Yb, Wprojb, bproj, nullptr, nullptr, nullptr, outf, 8192, 768, 768);
}

// Round 6
// 238.388 us; speedup vs baseline: 1.3315x; 1.1258x over previous
//
#include <hip/hip_runtime.h>

typedef unsigned short u16;
typedef unsigned int u32;
typedef __attribute__((ext_vector_type(8))) short short8;
typedef __attribute__((ext_vector_type(4))) short s16x4;
typedef __attribute__((ext_vector_type(4))) float f32x4;

__device__ __forceinline__ float b2f(u16 u) {
    union { u32 i; float f; } v; v.i = ((u32)u) << 16; return v.f;
}
__device__ __forceinline__ u16 f2b(float f) {
    union { u32 i; float f; } v; v.f = f;
    u32 u = v.i;
    return (u16)((u + 0x7FFFu + ((u >> 16) & 1u)) >> 16);
}
__device__ __forceinline__ f32x4 zero4() {
    f32x4 v; v[0] = 0.f; v[1] = 0.f; v[2] = 0.f; v[3] = 0.f; return v;
}
// packed f32x2 -> bf16x2 (RNE); low 16 bits = first arg (HW-verified R13/R15)
__device__ __forceinline__ u32 cvtpk(float lo, float hi) {
    u32 d;
    asm("v_cvt_pk_bf16_f32 %0, %1, %2" : "=v"(d) : "v"(lo), "v"(hi));
    return d;
}
__device__ __forceinline__ float fexp2(float x) {
#if __has_builtin(__builtin_amdgcn_exp2f)
    return __builtin_amdgcn_exp2f(x);
#else
    return __expf(x * 0.6931471805599453f);
#endif
}
// async global->LDS, 16B per lane: lane l's 16B land at ldsbase + l*16.
__device__ __forceinline__ void gload16(const u16* g, u16* l) {
    __builtin_amdgcn_global_load_lds(
        (const __attribute__((address_space(1))) u32*)g,
        (__attribute__((address_space(3))) u32*)l, 16, 0, 0);
}

// ---------------------------------------------------------------------------
// fp32 -> bf16 convert (x only).
// ---------------------------------------------------------------------------
__global__ void convert_kernel(const float* __restrict__ src, u16* __restrict__ dst,
                               int n8) {
    const int stride = gridDim.x * blockDim.x;
    for (int i = blockIdx.x * blockDim.x + threadIdx.x; i < n8; i += stride) {
        const float* s = src + (size_t)i * 8;
        float4 a = ((const float4*)s)[0];
        float4 b = ((const float4*)s)[1];
        short8 o;
        o[0] = (short)f2b(a.x); o[1] = (short)f2b(a.y);
        o[2] = (short)f2b(a.z); o[3] = (short)f2b(a.w);
        o[4] = (short)f2b(b.x); o[5] = (short)f2b(b.y);
        o[6] = (short)f2b(b.z); o[7] = (short)f2b(b.w);
        ((short8*)dst)[i] = o;
    }
}

// ---------------------------------------------------------------------------
// fp32 [K][N] -> bf16 [N][K] transpose-convert (weights, one-time).
// ---------------------------------------------------------------------------
__global__ void tconvert_kernel(const float* __restrict__ src, u16* __restrict__ dst,
                                int K, int N) {
    __shared__ u16 T[64][72];
    const int n0 = blockIdx.x * 64, k0 = blockIdx.y * 64;
    const int tid = threadIdx.x;
    const int r = tid >> 3, cq = tid & 7;   // r: 0..31, cq: 0..7
#pragma unroll
    for (int half = 0; half < 2; half++) {
        const int k = k0 + half * 32 + r;
        const float* s = &src[(size_t)k * N + n0 + cq * 8];
        const float4 f0 = ((const float4*)s)[0];
        const float4 f1 = ((const float4*)s)[1];
        T[cq * 8 + 0][half * 32 + r] = f2b(f0.x);
        T[cq * 8 + 1][half * 32 + r] = f2b(f0.y);
        T[cq * 8 + 2][half * 32 + r] = f2b(f0.z);
        T[cq * 8 + 3][half * 32 + r] = f2b(f0.w);
        T[cq * 8 + 4][half * 32 + r] = f2b(f1.x);
        T[cq * 8 + 5][half * 32 + r] = f2b(f1.y);
        T[cq * 8 + 6][half * 32 + r] = f2b(f1.z);
        T[cq * 8 + 7][half * 32 + r] = f2b(f1.w);
    }
    __syncthreads();
#pragma unroll
    for (int half = 0; half < 2; half++) {
        const int n = half * 32 + r;
        short8 o = *(const short8*)&T[n][cq * 8];
        *(short8*)&dst[(size_t)(n0 + n) * K + k0 + cq * 8] = o;
    }
}

// ---------------------------------------------------------------------------
// m97-structure GEMM (verified R16): C = A[M,K] x Bt[N,K]^T + bias[N].
// 128x128 tile, BK=32, global_load_lds width-16 staging, linear LDS.
// MODE 0: scatter bf16 into Q/K/V [b,h,s,d]. MODE 1: fp32 store to Of [M,N].
// XCD swizzle (T1): nwg = 1152 / 384, both % 8 == 0, bijective.
// ---------------------------------------------------------------------------
template <int MODE>
__global__ __launch_bounds__(256, 2) void gemm_bt_kernel(
    const u16* __restrict__ A, const u16* __restrict__ Bt,
    const float* __restrict__ bias,
    u16* __restrict__ O0, u16* __restrict__ O1, u16* __restrict__ O2,
    float* __restrict__ Of,
    int M, int N, int K)
{
    __shared__ u16 As[128 * 32];   // [m][k] linear (gload_lds dest: no pad)
    __shared__ u16 Bs[128 * 32];   // [n][k] linear

    const int tid = threadIdx.x;
    const int nwgx = gridDim.x;
    const int nwg = nwgx * gridDim.y;
    int lin = blockIdx.y * nwgx + blockIdx.x;
    lin = (lin & 7) * (nwg >> 3) + (lin >> 3);   // bijective: nwg % 8 == 0
    const int m0 = (lin / nwgx) * 128, n0 = (lin % nwgx) * 128;
    const int lane = tid & 63, w = tid >> 6;
    const int quad = lane >> 4, c = lane & 15;
    const int wm = (w & 1) * 64, wn = (w >> 1) * 64;

    f32x4 acc[4][4];
#pragma unroll
    for (int i = 0; i < 4; i++)
#pragma unroll
        for (int j = 0; j < 4; j++) acc[i][j] = zero4();

    const int grow = w * 32 + (lane >> 2);
    const int gcol = (lane & 3) * 8;
    const size_t abase = (size_t)(m0 + grow) * K + gcol;
    const size_t bbase = (size_t)(n0 + grow) * K + gcol;
    u16* asl = &As[w * 1024];      // wave-uniform LDS base
    u16* bsl = &Bs[w * 1024];

    for (int k0 = 0; k0 < K; k0 += 32) {
        __syncthreads();           // previous iteration's frag reads done
        gload16(A + abase + k0, asl);
        gload16(A + abase + (size_t)16 * K + k0, asl + 512);
        gload16(Bt + bbase + k0, bsl);
        gload16(Bt + bbase + (size_t)16 * K + k0, bsl + 512);
        asm volatile("s_waitcnt vmcnt(0)" ::: "memory");  // tile landed in LDS
        __syncthreads();

        short8 af[4], bfr[4];
#pragma unroll
        for (int mi = 0; mi < 4; mi++)
            af[mi] = *(const short8*)&As[(wm + mi * 16 + c) * 32 + quad * 8];
#pragma unroll
        for (int ni = 0; ni < 4; ni++)
            bfr[ni] = *(const short8*)&Bs[(wn + ni * 16 + c) * 32 + quad * 8];
#pragma unroll
        for (int mi = 0; mi < 4; mi++)
#pragma unroll
            for (int ni = 0; ni < 4; ni++)
                acc[mi][ni] = __builtin_amdgcn_mfma_f32_16x16x32_bf16(
                    af[mi], bfr[ni], acc[mi][ni], 0, 0, 0);
    }

#pragma unroll
    for (int ni = 0; ni < 4; ni++) {
        const int gc = n0 + wn + ni * 16 + c;
        const float bv = bias[gc];
        if (MODE == 0) {
            const int which = gc / 768;
            const int e = gc - which * 768;
            const int hh = e >> 6, d = e & 63;
            u16* op = (which == 0) ? O0 : (which == 1 ? O1 : O2);
#pragma unroll
            for (int mi = 0; mi < 4; mi++)
#pragma unroll
                for (int r = 0; r < 4; r++) {
                    const int gr = m0 + wm + mi * 16 + quad * 4 + r;
                    const int bb = gr >> 11, s = gr & 2047;
                    op[(((size_t)bb * 12 + hh) * 2048 + s) * 64 + d] =
                        f2b(acc[mi][ni][r] + bv);
                }
        } else {
#pragma unroll
            for (int mi = 0; mi < 4; mi++)
#pragma unroll
                for (int r = 0; r < 4; r++) {
                    const int gr = m0 + wm + mi * 16 + quad * 4 + r;
                    Of[(size_t)gr * N + gc] = acc[mi][ni][r] + bv;
                }
        }
    }
}

// ---------------------------------------------------------------------------
// Flash attention, KB=64, NO-MAX softmax.
// R17: 128 q-rows per block (2 q-groups per wave, rows q0+c and q0+64+c).
// Rationale (R16 counters: MfmaUtil 17.6, VALUBusy 38.7, HBM 3.4% -> both
// pipes idle, latency-bound on the per-tile serial chain x32 tiles):
//   - K/V staging, barriers, K-frag and V-frag ds_reads HALVED per q-row:
//     8 K-frag reads feed 16 MFMAs (in-register reuse across groups), same
//     for V-frags. MFMA per tile per wave 16 -> 32 (2x ILP between barriers).
//   - grid 768 blocks = exactly 3/CU in ONE residency shift (no tail).
// All mappings are the R15/R16-verified code replicated with +64 row offset
// and a group index on Ps; no new layout assumptions.
// Kept: swapped QK^T (lane-local P rows), cvtpk+b64 P stores, exp2-domain
// mask bias, T14 prefetch with raw barriers, T5 setprio.
// ---------------------------------------------------------------------------
__global__ __launch_bounds__(256, 3) void attn_kernel(
    const u16* __restrict__ Q, const u16* __restrict__ Kv,
    const u16* __restrict__ Vv, const int* __restrict__ attmask,
    u16* __restrict__ Y)
{
    const int S = 2048, D = 64, NH = 12;
    __shared__ u16 Ks[64][72];          // [pos][d]
    __shared__ u16 Vs[64][68];          // [d][pos]
    __shared__ u16 Ps[4][2][16][72];    // per-wave,per-group P: [qrow][pos]
    __shared__ float msf[2048];         // exp2-domain mask bias: 0 or -43282

    const int tid = threadIdx.x;
    const int w = tid >> 6, lane = tid & 63;
    const int quad = lane >> 4, c = lane & 15;
    const int bh = blockIdx.x;        // 0..47
    const int qt = blockIdx.y;        // 0..15
    const int b = bh / NH, h = bh - b * NH;

    const u16* Qh = Q + (size_t)bh * S * D;
    const u16* Kh = Kv + (size_t)bh * S * D;
    const u16* Vh = Vv + (size_t)bh * S * D;
    const int q0 = qt * 128 + w * 16;   // group 0; group 1 at q0+64

    short8 aq00 = *(const short8*)&Qh[(size_t)(q0 + c) * D + quad * 8];
    short8 aq01 = *(const short8*)&Qh[(size_t)(q0 + c) * D + 32 + quad * 8];
    short8 aq10 = *(const short8*)&Qh[(size_t)(q0 + 64 + c) * D + quad * 8];
    short8 aq11 = *(const short8*)&Qh[(size_t)(q0 + 64 + c) * D + 32 + quad * 8];

    for (int i = tid; i < S; i += 256)
        msf[i] = (attmask[b * S + i] == 0) ? -43282.0f : 0.0f;

    f32x4 o_acc[2][4];
#pragma unroll
    for (int g = 0; g < 2; g++)
#pragma unroll
        for (int i = 0; i < 4; i++) o_acc[g][i] = zero4();
    float l0 = 0.f, l1 = 0.f;

    const int kpos = tid >> 2, kd = (tid & 3) * 8;
    const int p2 = tid >> 3, vd = (tid & 7) * 8;

    // T14 prologue: issue tile-0 loads
    short8 k0r = *(const short8*)&Kh[(size_t)kpos * D + kd];
    short8 k1r = *(const short8*)&Kh[(size_t)kpos * D + kd + 32];
    short8 v0r = *(const short8*)&Vh[(size_t)(2 * p2) * D + vd];
    short8 v1r = *(const short8*)&Vh[(size_t)(2 * p2 + 1) * D + vd];

    const float SC = 0.18033688f;  // 0.125 * log2(e)

    for (int kt = 0; kt < S / 64; kt++) {
        // ---- staging (raw barriers: vmcnt NOT drained -> prefetch in flight)
        asm volatile("" ::: "memory");
        __builtin_amdgcn_s_barrier();
        asm volatile("" ::: "memory");
        *(short8*)&Ks[kpos][kd] = k0r;
        *(short8*)&Ks[kpos][kd + 32] = k1r;
#pragma unroll
        for (int j = 0; j < 8; j++) {
            u32 pk = (u32)(u16)v0r[j] | ((u32)(u16)v1r[j] << 16);
            *(u32*)&Vs[vd + j][2 * p2] = pk;
        }
        if (kt + 1 < S / 64) {
            const int nb = (kt + 1) * 64;
            k0r = *(const short8*)&Kh[(size_t)(nb + kpos) * D + kd];
            k1r = *(const short8*)&Kh[(size_t)(nb + kpos) * D + kd + 32];
            v0r = *(const short8*)&Vh[(size_t)(nb + 2 * p2) * D + vd];
            v1r = *(const short8*)&Vh[(size_t)(nb + 2 * p2 + 1) * D + vd];
        }
        asm volatile("s_waitcnt lgkmcnt(0)" ::: "memory");
        __builtin_amdgcn_s_barrier();
        asm volatile("" ::: "memory");

        const int kbase = kt * 64;

        // ---- QK^T, swapped: s_acc[g][ni] = S[kpos=ni*16+quad*4+r][q-group g]
        f32x4 s0[4], s1[4];
#pragma unroll
        for (int ni = 0; ni < 4; ni++) { s0[ni] = zero4(); s1[ni] = zero4(); }
        __builtin_amdgcn_s_setprio(1);
#pragma unroll
        for (int ni = 0; ni < 4; ni++) {
            short8 bk0 = *(const short8*)&Ks[ni * 16 + c][quad * 8];
            short8 bk1 = *(const short8*)&Ks[ni * 16 + c][32 + quad * 8];
            s0[ni] = __builtin_amdgcn_mfma_f32_16x16x32_bf16(bk0, aq00, s0[ni], 0, 0, 0);
            s0[ni] = __builtin_amdgcn_mfma_f32_16x16x32_bf16(bk1, aq01, s0[ni], 0, 0, 0);
            s1[ni] = __builtin_amdgcn_mfma_f32_16x16x32_bf16(bk0, aq10, s1[ni], 0, 0, 0);
            s1[ni] = __builtin_amdgcn_mfma_f32_16x16x32_bf16(bk1, aq11, s1[ni], 0, 0, 0);
        }
        __builtin_amdgcn_s_setprio(0);

        // ---- softmax per group: cvtpk pairs + one b64 store per (g,ni) ----
#pragma unroll
        for (int ni = 0; ni < 4; ni++) {
            const f32x4 bias = *(const f32x4*)&msf[kbase + ni * 16 + quad * 4];
            {
                float p0 = fexp2(fmaf(s0[ni][0], SC, bias[0]));
                float p1 = fexp2(fmaf(s0[ni][1], SC, bias[1]));
                float p2f = fexp2(fmaf(s0[ni][2], SC, bias[2]));
                float p3 = fexp2(fmaf(s0[ni][3], SC, bias[3]));
                l0 += (p0 + p1) + (p2f + p3);
                uint2 pk;
                pk.x = cvtpk(p0, p1);
                pk.y = cvtpk(p2f, p3);
                *(uint2*)&Ps[w][0][c][ni * 16 + quad * 4] = pk;
            }
            {
                float p0 = fexp2(fmaf(s1[ni][0], SC, bias[0]));
                float p1 = fexp2(fmaf(s1[ni][1], SC, bias[1]));
                float p2f = fexp2(fmaf(s1[ni][2], SC, bias[2]));
                float p3 = fexp2(fmaf(s1[ni][3], SC, bias[3]));
                l1 += (p0 + p1) + (p2f + p3);
                uint2 pk;
                pk.x = cvtpk(p0, p1);
                pk.y = cvtpk(p2f, p3);
                *(uint2*)&Ps[w][1][c][ni * 16 + quad * 4] = pk;
            }
        }
        // Ps is per-wave: in-order DS pipeline orders stores before our reads.

        short8 ap00 = *(const short8*)&Ps[w][0][c][quad * 8];
        short8 ap01 = *(const short8*)&Ps[w][0][c][32 + quad * 8];
        short8 ap10 = *(const short8*)&Ps[w][1][c][quad * 8];
        short8 ap11 = *(const short8*)&Ps[w][1][c][32 + quad * 8];
        __builtin_amdgcn_s_setprio(1);
#pragma unroll
        for (int ni = 0; ni < 4; ni++) {
            union { short8 v8; s16x4 v4[2]; } u0, u1;
            u0.v4[0] = *(const s16x4*)&Vs[ni * 16 + c][quad * 8];
            u0.v4[1] = *(const s16x4*)&Vs[ni * 16 + c][quad * 8 + 4];
            u1.v4[0] = *(const s16x4*)&Vs[ni * 16 + c][32 + quad * 8];
            u1.v4[1] = *(const s16x4*)&Vs[ni * 16 + c][32 + quad * 8 + 4];
            o_acc[0][ni] = __builtin_amdgcn_mfma_f32_16x16x32_bf16(ap00, u0.v8, o_acc[0][ni], 0, 0, 0);
            o_acc[0][ni] = __builtin_amdgcn_mfma_f32_16x16x32_bf16(ap01, u1.v8, o_acc[0][ni], 0, 0, 0);
            o_acc[1][ni] = __builtin_amdgcn_mfma_f32_16x16x32_bf16(ap10, u0.v8, o_acc[1][ni], 0, 0, 0);
            o_acc[1][ni] = __builtin_amdgcn_mfma_f32_16x16x32_bf16(ap11, u1.v8, o_acc[1][ni], 0, 0, 0);
        }
        __builtin_amdgcn_s_setprio(0);
    }

    // full row-sums: quads hold disjoint kpos subsets of row c
    l0 += __shfl_xor(l0, 16);
    l0 += __shfl_xor(l0, 32);
    l1 += __shfl_xor(l1, 16);
    l1 += __shfl_xor(l1, 32);

    const size_t ybase = ((size_t)b * S) * 768 + h * 64;
#pragma unroll
    for (int r = 0; r < 4; r++) {
        const float lr0 = __shfl(l0, quad * 4 + r);
        const float lr1 = __shfl(l1, quad * 4 + r);
        const float inv0 = 1.f / fmaxf(lr0, 1e-30f);
        const float inv1 = 1.f / fmaxf(lr1, 1e-30f);
        const int srow0 = qt * 128 + w * 16 + quad * 4 + r;
        const int srow1 = srow0 + 64;
#pragma unroll
        for (int ni = 0; ni < 4; ni++) {
            Y[ybase + (size_t)srow0 * 768 + ni * 16 + c] = f2b(o_acc[0][ni][r] * inv0);
            Y[ybase + (size_t)srow1 * 768 + ni * 16 + c] = f2b(o_acc[1][ni][r] * inv1);
        }
    }
}

extern "C" void kernel_launch(void* const* d_in, const int* in_sizes, int n_in,
                              void* d_out, int out_size, void* d_ws, size_t ws_size,
                              hipStream_t stream) {
    const float* x     = (const float*)d_in[0];
    const int* attmask = (const int*)d_in[1];
    const float* Wqkv  = (const float*)d_in[2];
    const float* bqkv  = (const float*)d_in[3];
    const float* Wproj = (const float*)d_in[4];
    const float* bproj = (const float*)d_in[5];
    float* outf = (float*)d_out;

    // ws layout: bf16 staging + intermediates (all fully rewritten per launch)
    u16* base = (u16*)d_ws;
    const size_t nx = 4ull * 2048 * 768;       // 6,291,456
    const size_t nwqkv = 768ull * 2304;        // 1,769,472
    const size_t nwproj = 768ull * 768;        // 589,824
    u16* xb     = base;
    u16* Wqkvb  = xb + nx;          // TRANSPOSED: [2304][768]
    u16* Wprojb = Wqkvb + nwqkv;    // TRANSPOSED: [768][768]
    u16* Qb     = Wprojb + nwproj;
    const size_t headElems = 48ull * 2048 * 64;  // 6,291,456
    u16* Kb = Qb + headElems;
    u16* Vb = Kb + headElems;
    u16* Yb = Vb + headElems;

    {
        int n8 = (int)(nx / 8);
        int blocks = (n8 + 255) / 256;
        if (blocks > 1024) blocks = 1024;
        convert_kernel<<<blocks, 256, 0, stream>>>(x, xb, n8);
    }
    // weights: fp32 [K][N] -> bf16 [N][K] (transpose-convert, one-time)
    tconvert_kernel<<<dim3(2304 / 64, 768 / 64), 256, 0, stream>>>(Wqkv, Wqkvb, 768, 2304);
    tconvert_kernel<<<dim3(768 / 64, 768 / 64), 256, 0, stream>>>(Wproj, Wprojb, 768, 768);

    // QKV GEMM: [8192,768] x [2304,768]^T + bias -> Q/K/V [b,h,s,d] bf16
    gemm_bt_kernel<0><<<dim3(18, 64), 256, 0, stream>>>(
        xb, Wqkvb, bqkv, Qb, Kb, Vb, nullptr, 8192, 2304, 768);
    // Flash attention -> Y [b,s,768] bf16 (128 q-rows per block)
    attn_kernel<<<dim3(48, 16), 256, 0, stream>>>(Qb, Kb, Vb, attmask, Yb);
    // Proj GEMM: [8192,768] x [768,768]^T + bias -> d_out fp32
    gemm_bt_kernel<1><<<dim3(6, 64), 256, 0, stream>>>(
        Yb, Wprojb, bproj, nullptr, nullptr, nullptr, outf, 8192, 768, 768);
}

// Round 7
// 227.809 us; speedup vs baseline: 1.3933x; 1.0464x over previous
//
#include <hip/hip_runtime.h>

typedef unsigned short u16;
typedef unsigned int u32;
typedef __attribute__((ext_vector_type(8))) short short8;
typedef __attribute__((ext_vector_type(4))) short s16x4;
typedef __attribute__((ext_vector_type(4))) float f32x4;

__device__ __forceinline__ float b2f(u16 u) {
    union { u32 i; float f; } v; v.i = ((u32)u) << 16; return v.f;
}
__device__ __forceinline__ u16 f2b(float f) {
    union { u32 i; float f; } v; v.f = f;
    u32 u = v.i;
    return (u16)((u + 0x7FFFu + ((u >> 16) & 1u)) >> 16);
}
__device__ __forceinline__ f32x4 zero4() {
    f32x4 v; v[0] = 0.f; v[1] = 0.f; v[2] = 0.f; v[3] = 0.f; return v;
}
// packed f32x2 -> bf16x2 (RNE); low 16 bits = first arg (HW-verified R13/R15)
__device__ __forceinline__ u32 cvtpk(float lo, float hi) {
    u32 d;
    asm("v_cvt_pk_bf16_f32 %0, %1, %2" : "=v"(d) : "v"(lo), "v"(hi));
    return d;
}
__device__ __forceinline__ float fexp2(float x) {
#if __has_builtin(__builtin_amdgcn_exp2f)
    return __builtin_amdgcn_exp2f(x);
#else
    return __expf(x * 0.6931471805599453f);
#endif
}
// async global->LDS, 16B per lane: lane l's 16B land at ldsbase + l*16.
__device__ __forceinline__ void gload16(const u16* g, u16* l) {
    __builtin_amdgcn_global_load_lds(
        (const __attribute__((address_space(1))) u32*)g,
        (__attribute__((address_space(3))) u32*)l, 16, 0, 0);
}

// ---------------------------------------------------------------------------
// Merged prep kernel (R18: one launch instead of three).
// blocks [0,432):   Wqkv fp32 [768][2304] -> bf16 [2304][768] transpose
// blocks [432,576): Wproj fp32 [768][768] -> bf16 [768][768] transpose
// blocks [576,1152): x fp32 -> bf16 linear convert (grid-stride)
// ---------------------------------------------------------------------------
__device__ __forceinline__ void tconv_body(const float* __restrict__ src,
                                           u16* __restrict__ dst,
                                           int K, int N, int bx, int by) {
    __shared__ u16 T[64][72];
    const int n0 = bx * 64, k0 = by * 64;
    const int tid = threadIdx.x;
    const int r = tid >> 3, cq = tid & 7;   // r: 0..31, cq: 0..7
#pragma unroll
    for (int half = 0; half < 2; half++) {
        const int k = k0 + half * 32 + r;
        const float* s = &src[(size_t)k * N + n0 + cq * 8];
        const float4 f0 = ((const float4*)s)[0];
        const float4 f1 = ((const float4*)s)[1];
        T[cq * 8 + 0][half * 32 + r] = f2b(f0.x);
        T[cq * 8 + 1][half * 32 + r] = f2b(f0.y);
        T[cq * 8 + 2][half * 32 + r] = f2b(f0.z);
        T[cq * 8 + 3][half * 32 + r] = f2b(f0.w);
        T[cq * 8 + 4][half * 32 + r] = f2b(f1.x);
        T[cq * 8 + 5][half * 32 + r] = f2b(f1.y);
        T[cq * 8 + 6][half * 32 + r] = f2b(f1.z);
        T[cq * 8 + 7][half * 32 + r] = f2b(f1.w);
    }
    __syncthreads();
#pragma unroll
    for (int half = 0; half < 2; half++) {
        const int n = half * 32 + r;
        short8 o = *(const short8*)&T[n][cq * 8];
        *(short8*)&dst[(size_t)(n0 + n) * K + k0 + cq * 8] = o;
    }
}

__global__ void prep_kernel(const float* __restrict__ x, u16* __restrict__ xb,
                            const float* __restrict__ Wqkv, u16* __restrict__ Wqkvb,
                            const float* __restrict__ Wproj, u16* __restrict__ Wprojb,
                            int n8x) {
    const int blk = blockIdx.x;
    if (blk < 432) {
        tconv_body(Wqkv, Wqkvb, 768, 2304, blk % 36, blk / 36);
    } else if (blk < 576) {
        const int id = blk - 432;
        tconv_body(Wproj, Wprojb, 768, 768, id % 12, id / 12);
    } else {
        const int stride = (1152 - 576) * 256;
        for (int i = (blk - 576) * 256 + threadIdx.x; i < n8x; i += stride) {
            const float* s = x + (size_t)i * 8;
            float4 a = ((const float4*)s)[0];
            float4 b = ((const float4*)s)[1];
            short8 o;
            o[0] = (short)f2b(a.x); o[1] = (short)f2b(a.y);
            o[2] = (short)f2b(a.z); o[3] = (short)f2b(a.w);
            o[4] = (short)f2b(b.x); o[5] = (short)f2b(b.y);
            o[6] = (short)f2b(b.z); o[7] = (short)f2b(b.w);
            ((short8*)xb)[i] = o;
        }
    }
}

// ---------------------------------------------------------------------------
// m97-structure GEMM, R18: BK=64 (barrier pairs halved, 24 -> 12 per tile;
// the per-K-step vmcnt(0)+double-barrier drain is the structure's known ~20%
// stall). LDS 32 KB -> occupancy unchanged at bound 2 (m132's regression was
// the 64 KB cliff, not BK itself).
// Linear [128][64] would be a 16-lane b128 conflict (stride 128 B: row term
// vanishes mod 8 slots) -> chunk-parity XOR swizzle, both-sides (rule 21):
//   write: gload source col = ((lane&7) ^ ((lane>>3&1)<<2)) * 8
//          (same 128 B row segment -> coalescing preserved)
//   read:  A[row][k-chunk kk*4+quad] sits at LDS col ((kk*4+quad)^((row&1)<<2))*8
// Verified by hand: same involution both sides; read = 8 lanes/slot = b128
// floor (conflict-free). MODE 0: scatter bf16 into Q/K/V. MODE 1: fp32 out.
// XCD swizzle (T1): nwg = 1152 / 384, both % 8 == 0, bijective.
// ---------------------------------------------------------------------------
template <int MODE>
__global__ __launch_bounds__(256, 2) void gemm_bt_kernel(
    const u16* __restrict__ A, const u16* __restrict__ Bt,
    const float* __restrict__ bias,
    u16* __restrict__ O0, u16* __restrict__ O1, u16* __restrict__ O2,
    float* __restrict__ Of,
    int M, int N, int K)
{
    __shared__ u16 As[128 * 64];   // [m][k] linear+swizzled (gload_lds dest)
    __shared__ u16 Bs[128 * 64];   // [n][k]

    const int tid = threadIdx.x;
    const int nwgx = gridDim.x;
    const int nwg = nwgx * gridDim.y;
    int lin = blockIdx.y * nwgx + blockIdx.x;
    lin = (lin & 7) * (nwg >> 3) + (lin >> 3);   // bijective: nwg % 8 == 0
    const int m0 = (lin / nwgx) * 128, n0 = (lin % nwgx) * 128;
    const int lane = tid & 63, w = tid >> 6;
    const int quad = lane >> 4, c = lane & 15;
    const int wm = (w & 1) * 64, wn = (w >> 1) * 64;

    f32x4 acc[4][4];
#pragma unroll
    for (int i = 0; i < 4; i++)
#pragma unroll
        for (int j = 0; j < 4; j++) acc[i][j] = zero4();

    // staging: wave w covers rows [w*32, w*32+32) x 64 k per tile.
    // instr i: 8 rows (w*32+i*8+(lane>>3)), source col pre-swizzled.
    const int srow = lane >> 3;                         // 0..7
    const int scol = ((lane & 7) ^ ((srow & 1) << 2)) * 8;  // pre-swizzled
    const size_t abase = (size_t)(m0 + w * 32 + srow) * K + scol;
    const size_t bbase = (size_t)(n0 + w * 32 + srow) * K + scol;
    u16* asl = &As[w * 32 * 64];   // wave-uniform LDS base
    u16* bsl = &Bs[w * 32 * 64];

    const int cpar = (c & 1) << 2;   // read-side swizzle term

    for (int k0 = 0; k0 < K; k0 += 64) {
        __syncthreads();           // previous iteration's frag reads done
#pragma unroll
        for (int i = 0; i < 4; i++)
            gload16(A + abase + (size_t)(i * 8) * K + k0, asl + i * 512);
#pragma unroll
        for (int i = 0; i < 4; i++)
            gload16(Bt + bbase + (size_t)(i * 8) * K + k0, bsl + i * 512);
        asm volatile("s_waitcnt vmcnt(0)" ::: "memory");  // tile landed in LDS
        __syncthreads();

        short8 af[4][2], bfr[4][2];
#pragma unroll
        for (int mi = 0; mi < 4; mi++)
#pragma unroll
            for (int kk = 0; kk < 2; kk++)
                af[mi][kk] = *(const short8*)
                    &As[(wm + mi * 16 + c) * 64 + (((kk * 4 + quad) ^ cpar) * 8)];
#pragma unroll
        for (int ni = 0; ni < 4; ni++)
#pragma unroll
            for (int kk = 0; kk < 2; kk++)
                bfr[ni][kk] = *(const short8*)
                    &Bs[(wn + ni * 16 + c) * 64 + (((kk * 4 + quad) ^ cpar) * 8)];
#pragma unroll
        for (int kk = 0; kk < 2; kk++)
#pragma unroll
            for (int mi = 0; mi < 4; mi++)
#pragma unroll
                for (int ni = 0; ni < 4; ni++)
                    acc[mi][ni] = __builtin_amdgcn_mfma_f32_16x16x32_bf16(
                        af[mi][kk], bfr[ni][kk], acc[mi][ni], 0, 0, 0);
    }

#pragma unroll
    for (int ni = 0; ni < 4; ni++) {
        const int gc = n0 + wn + ni * 16 + c;
        const float bv = bias[gc];
        if (MODE == 0) {
            const int which = gc / 768;
            const int e = gc - which * 768;
            const int hh = e >> 6, d = e & 63;
            u16* op = (which == 0) ? O0 : (which == 1 ? O1 : O2);
#pragma unroll
            for (int mi = 0; mi < 4; mi++)
#pragma unroll
                for (int r = 0; r < 4; r++) {
                    const int gr = m0 + wm + mi * 16 + quad * 4 + r;
                    const int bb = gr >> 11, s = gr & 2047;
                    op[(((size_t)bb * 12 + hh) * 2048 + s) * 64 + d] =
                        f2b(acc[mi][ni][r] + bv);
                }
        } else {
#pragma unroll
            for (int mi = 0; mi < 4; mi++)
#pragma unroll
                for (int r = 0; r < 4; r++) {
                    const int gr = m0 + wm + mi * 16 + quad * 4 + r;
                    Of[(size_t)gr * N + gc] = acc[mi][ni][r] + bv;
                }
        }
    }
}

// ---------------------------------------------------------------------------
// Flash attention — UNCHANGED from R17 (verified passing, 89.3 us):
// 128 q-rows/block (2 groups/wave), swapped QK^T, cvtpk+b64 P stores,
// exp2-domain mask bias, T14 prefetch with raw barriers, T5 setprio.
// R18 pipe accounting: VALU 36% + MFMA 24% + trans ~10% + LDS ~30% ->
// multi-pipe saturated for this structure; frozen.
// ---------------------------------------------------------------------------
__global__ __launch_bounds__(256, 3) void attn_kernel(
    const u16* __restrict__ Q, const u16* __restrict__ Kv,
    const u16* __restrict__ Vv, const int* __restrict__ attmask,
    u16* __restrict__ Y)
{
    const int S = 2048, D = 64, NH = 12;
    __shared__ u16 Ks[64][72];          // [pos][d]
    __shared__ u16 Vs[64][68];          // [d][pos]
    __shared__ u16 Ps[4][2][16][72];    // per-wave,per-group P: [qrow][pos]
    __shared__ float msf[2048];         // exp2-domain mask bias: 0 or -43282

    const int tid = threadIdx.x;
    const int w = tid >> 6, lane = tid & 63;
    const int quad = lane >> 4, c = lane & 15;
    const int bh = blockIdx.x;        // 0..47
    const int qt = blockIdx.y;        // 0..15
    const int b = bh / NH, h = bh - b * NH;

    const u16* Qh = Q + (size_t)bh * S * D;
    const u16* Kh = Kv + (size_t)bh * S * D;
    const u16* Vh = Vv + (size_t)bh * S * D;
    const int q0 = qt * 128 + w * 16;   // group 0; group 1 at q0+64

    short8 aq00 = *(const short8*)&Qh[(size_t)(q0 + c) * D + quad * 8];
    short8 aq01 = *(const short8*)&Qh[(size_t)(q0 + c) * D + 32 + quad * 8];
    short8 aq10 = *(const short8*)&Qh[(size_t)(q0 + 64 + c) * D + quad * 8];
    short8 aq11 = *(const short8*)&Qh[(size_t)(q0 + 64 + c) * D + 32 + quad * 8];

    for (int i = tid; i < S; i += 256)
        msf[i] = (attmask[b * S + i] == 0) ? -43282.0f : 0.0f;

    f32x4 o_acc[2][4];
#pragma unroll
    for (int g = 0; g < 2; g++)
#pragma unroll
        for (int i = 0; i < 4; i++) o_acc[g][i] = zero4();
    float l0 = 0.f, l1 = 0.f;

    const int kpos = tid >> 2, kd = (tid & 3) * 8;
    const int p2 = tid >> 3, vd = (tid & 7) * 8;

    // T14 prologue: issue tile-0 loads
    short8 k0r = *(const short8*)&Kh[(size_t)kpos * D + kd];
    short8 k1r = *(const short8*)&Kh[(size_t)kpos * D + kd + 32];
    short8 v0r = *(const short8*)&Vh[(size_t)(2 * p2) * D + vd];
    short8 v1r = *(const short8*)&Vh[(size_t)(2 * p2 + 1) * D + vd];

    const float SC = 0.18033688f;  // 0.125 * log2(e)

    for (int kt = 0; kt < S / 64; kt++) {
        // ---- staging (raw barriers: vmcnt NOT drained -> prefetch in flight)
        asm volatile("" ::: "memory");
        __builtin_amdgcn_s_barrier();
        asm volatile("" ::: "memory");
        *(short8*)&Ks[kpos][kd] = k0r;
        *(short8*)&Ks[kpos][kd + 32] = k1r;
#pragma unroll
        for (int j = 0; j < 8; j++) {
            u32 pk = (u32)(u16)v0r[j] | ((u32)(u16)v1r[j] << 16);
            *(u32*)&Vs[vd + j][2 * p2] = pk;
        }
        if (kt + 1 < S / 64) {
            const int nb = (kt + 1) * 64;
            k0r = *(const short8*)&Kh[(size_t)(nb + kpos) * D + kd];
            k1r = *(const short8*)&Kh[(size_t)(nb + kpos) * D + kd + 32];
            v0r = *(const short8*)&Vh[(size_t)(nb + 2 * p2) * D + vd];
            v1r = *(const short8*)&Vh[(size_t)(nb + 2 * p2 + 1) * D + vd];
        }
        asm volatile("s_waitcnt lgkmcnt(0)" ::: "memory");
        __builtin_amdgcn_s_barrier();
        asm volatile("" ::: "memory");

        const int kbase = kt * 64;

        // ---- QK^T, swapped: s[g][ni] = S[kpos=ni*16+quad*4+r][q-group g]
        f32x4 s0[4], s1[4];
#pragma unroll
        for (int ni = 0; ni < 4; ni++) { s0[ni] = zero4(); s1[ni] = zero4(); }
        __builtin_amdgcn_s_setprio(1);
#pragma unroll
        for (int ni = 0; ni < 4; ni++) {
            short8 bk0 = *(const short8*)&Ks[ni * 16 + c][quad * 8];
            short8 bk1 = *(const short8*)&Ks[ni * 16 + c][32 + quad * 8];
            s0[ni] = __builtin_amdgcn_mfma_f32_16x16x32_bf16(bk0, aq00, s0[ni], 0, 0, 0);
            s0[ni] = __builtin_amdgcn_mfma_f32_16x16x32_bf16(bk1, aq01, s0[ni], 0, 0, 0);
            s1[ni] = __builtin_amdgcn_mfma_f32_16x16x32_bf16(bk0, aq10, s1[ni], 0, 0, 0);
            s1[ni] = __builtin_amdgcn_mfma_f32_16x16x32_bf16(bk1, aq11, s1[ni], 0, 0, 0);
        }
        __builtin_amdgcn_s_setprio(0);

        // ---- softmax per group: cvtpk pairs + one b64 store per (g,ni) ----
#pragma unroll
        for (int ni = 0; ni < 4; ni++) {
            const f32x4 bias = *(const f32x4*)&msf[kbase + ni * 16 + quad * 4];
            {
                float p0 = fexp2(fmaf(s0[ni][0], SC, bias[0]));
                float p1 = fexp2(fmaf(s0[ni][1], SC, bias[1]));
                float p2f = fexp2(fmaf(s0[ni][2], SC, bias[2]));
                float p3 = fexp2(fmaf(s0[ni][3], SC, bias[3]));
                l0 += (p0 + p1) + (p2f + p3);
                uint2 pk;
                pk.x = cvtpk(p0, p1);
                pk.y = cvtpk(p2f, p3);
                *(uint2*)&Ps[w][0][c][ni * 16 + quad * 4] = pk;
            }
            {
                float p0 = fexp2(fmaf(s1[ni][0], SC, bias[0]));
                float p1 = fexp2(fmaf(s1[ni][1], SC, bias[1]));
                float p2f = fexp2(fmaf(s1[ni][2], SC, bias[2]));
                float p3 = fexp2(fmaf(s1[ni][3], SC, bias[3]));
                l1 += (p0 + p1) + (p2f + p3);
                uint2 pk;
                pk.x = cvtpk(p0, p1);
                pk.y = cvtpk(p2f, p3);
                *(uint2*)&Ps[w][1][c][ni * 16 + quad * 4] = pk;
            }
        }
        // Ps is per-wave: in-order DS pipeline orders stores before our reads.

        short8 ap00 = *(const short8*)&Ps[w][0][c][quad * 8];
        short8 ap01 = *(const short8*)&Ps[w][0][c][32 + quad * 8];
        short8 ap10 = *(const short8*)&Ps[w][1][c][quad * 8];
        short8 ap11 = *(const short8*)&Ps[w][1][c][32 + quad * 8];
        __builtin_amdgcn_s_setprio(1);
#pragma unroll
        for (int ni = 0; ni < 4; ni++) {
            union { short8 v8; s16x4 v4[2]; } u0, u1;
            u0.v4[0] = *(const s16x4*)&Vs[ni * 16 + c][quad * 8];
            u0.v4[1] = *(const s16x4*)&Vs[ni * 16 + c][quad * 8 + 4];
            u1.v4[0] = *(const s16x4*)&Vs[ni * 16 + c][32 + quad * 8];
            u1.v4[1] = *(const s16x4*)&Vs[ni * 16 + c][32 + quad * 8 + 4];
            o_acc[0][ni] = __builtin_amdgcn_mfma_f32_16x16x32_bf16(ap00, u0.v8, o_acc[0][ni], 0, 0, 0);
            o_acc[0][ni] = __builtin_amdgcn_mfma_f32_16x16x32_bf16(ap01, u1.v8, o_acc[0][ni], 0, 0, 0);
            o_acc[1][ni] = __builtin_amdgcn_mfma_f32_16x16x32_bf16(ap10, u0.v8, o_acc[1][ni], 0, 0, 0);
            o_acc[1][ni] = __builtin_amdgcn_mfma_f32_16x16x32_bf16(ap11, u1.v8, o_acc[1][ni], 0, 0, 0);
        }
        __builtin_amdgcn_s_setprio(0);
    }

    // full row-sums: quads hold disjoint kpos subsets of row c
    l0 += __shfl_xor(l0, 16);
    l0 += __shfl_xor(l0, 32);
    l1 += __shfl_xor(l1, 16);
    l1 += __shfl_xor(l1, 32);

    const size_t ybase = ((size_t)b * S) * 768 + h * 64;
#pragma unroll
    for (int r = 0; r < 4; r++) {
        const float lr0 = __shfl(l0, quad * 4 + r);
        const float lr1 = __shfl(l1, quad * 4 + r);
        const float inv0 = 1.f / fmaxf(lr0, 1e-30f);
        const float inv1 = 1.f / fmaxf(lr1, 1e-30f);
        const int srow0 = qt * 128 + w * 16 + quad * 4 + r;
        const int srow1 = srow0 + 64;
#pragma unroll
        for (int ni = 0; ni < 4; ni++) {
            Y[ybase + (size_t)srow0 * 768 + ni * 16 + c] = f2b(o_acc[0][ni][r] * inv0);
            Y[ybase + (size_t)srow1 * 768 + ni * 16 + c] = f2b(o_acc[1][ni][r] * inv1);
        }
    }
}

extern "C" void kernel_launch(void* const* d_in, const int* in_sizes, int n_in,
                              void* d_out, int out_size, void* d_ws, size_t ws_size,
                              hipStream_t stream) {
    const float* x     = (const float*)d_in[0];
    const int* attmask = (const int*)d_in[1];
    const float* Wqkv  = (const float*)d_in[2];
    const float* bqkv  = (const float*)d_in[3];
    const float* Wproj = (const float*)d_in[4];
    const float* bproj = (const float*)d_in[5];
    float* outf = (float*)d_out;

    // ws layout: bf16 staging + intermediates (all fully rewritten per launch)
    u16* base = (u16*)d_ws;
    const size_t nx = 4ull * 2048 * 768;       // 6,291,456
    const size_t nwqkv = 768ull * 2304;        // 1,769,472
    const size_t nwproj = 768ull * 768;        // 589,824
    u16* xb     = base;
    u16* Wqkvb  = xb + nx;          // TRANSPOSED: [2304][768]
    u16* Wprojb = Wqkvb + nwqkv;    // TRANSPOSED: [768][768]
    u16* Qb     = Wprojb + nwproj;
    const size_t headElems = 48ull * 2048 * 64;  // 6,291,456
    u16* Kb = Qb + headElems;
    u16* Vb = Kb + headElems;
    u16* Yb = Vb + headElems;

    // single prep launch: both weight transposes + x convert
    prep_kernel<<<1152, 256, 0, stream>>>(x, xb, Wqkv, Wqkvb, Wproj, Wprojb,
                                          (int)(nx / 8));

    // QKV GEMM: [8192,768] x [2304,768]^T + bias -> Q/K/V [b,h,s,d] bf16
    gemm_bt_kernel<0><<<dim3(18, 64), 256, 0, stream>>>(
        xb, Wqkvb, bqkv, Qb, Kb, Vb, nullptr, 8192, 2304, 768);
    // Flash attention -> Y [b,s,768] bf16 (128 q-rows per block)
    attn_kernel<<<dim3(48, 16), 256, 0, stream>>>(Qb, Kb, Vb, attmask, Yb);
    // Proj GEMM: [8192,768] x [768,768]^T + bias -> d_out fp32
    gemm_bt_kernel<1><<<dim3(6, 64), 256, 0, stream>>>(
        Yb, Wprojb, bproj, nullptr, nullptr, nullptr, outf, 8192, 768, 768);
}